// Round 7
// baseline (777.136 us; speedup 1.0000x reference)
//
#include <hip/hip_runtime.h>
#include <math.h>

#define NPTS 500000
#define KH 129
#define NKEY 16384   // 32x32x16 cells of 8x8x16 voxels
#define LSTR 260     // LDS line stride (floats): 16B-aligned, breaks pow2 conflicts
#define TILE 4096    // 256*16 float2 per (x|y, kb) tile

// ---------------- radix-16 x radix-16 register FFT ----------------
template<int SIGN>
__device__ __forceinline__ void dft4v(float& ar, float& ai, float& br, float& bi,
                                      float& cr, float& ci, float& dr, float& di) {
    float t0r = ar + cr, t0i = ai + ci;
    float t1r = ar - cr, t1i = ai - ci;
    float t2r = br + dr, t2i = bi + di;
    float t3r = br - dr, t3i = bi - di;
    ar = t0r + t2r; ai = t0i + t2i;
    cr = t0r - t2r; ci = t0i - t2i;
    if (SIGN < 0) { br = t1r + t3i; bi = t1i - t3r; dr = t1r - t3i; di = t1i + t3r; }
    else          { br = t1r - t3i; bi = t1i + t3r; dr = t1r + t3i; di = t1i - t3r; }
}

template<int SIGN>
__device__ __forceinline__ void twmul(float& r, float& i, float c, float s) {
    float s_ = (SIGN < 0) ? -s : s;
    float ar = r, ai = i;
    r = ar * c - ai * s_;
    i = ar * s_ + ai * c;
}

// 16-pt DFT, natural input v[0..15]; output X[k] lands in slot perm4(k)=((k&3)<<2)|(k>>2)
template<int SIGN>
__device__ __forceinline__ void dft16(float* vr, float* vi) {
    #pragma unroll
    for (int n2 = 0; n2 < 4; n2++)
        dft4v<SIGN>(vr[n2], vi[n2], vr[n2+4], vi[n2+4], vr[n2+8], vi[n2+8], vr[n2+12], vi[n2+12]);
    const float C1 = 0.923879532511287f, S1 = 0.382683432365090f;
    const float C2 = 0.707106781186548f, S2 = 0.707106781186548f;
    const float C3 = 0.382683432365090f, S3 = 0.923879532511287f;
    twmul<SIGN>(vr[5],  vi[5],  C1, S1);
    twmul<SIGN>(vr[6],  vi[6],  C2, S2);
    twmul<SIGN>(vr[7],  vi[7],  C3, S3);
    twmul<SIGN>(vr[9],  vi[9],  C2, S2);
    twmul<SIGN>(vr[10], vi[10], 0.0f, 1.0f);
    twmul<SIGN>(vr[11], vi[11], -C2, S2);
    twmul<SIGN>(vr[13], vi[13], C3, S3);
    twmul<SIGN>(vr[14], vi[14], -C2, S2);
    twmul<SIGN>(vr[15], vi[15], -C1, -S1);
    #pragma unroll
    for (int k1 = 0; k1 < 4; k1++)
        dft4v<SIGN>(vr[4*k1], vi[4*k1], vr[4*k1+1], vi[4*k1+1],
                    vr[4*k1+2], vi[4*k1+2], vr[4*k1+3], vi[4*k1+3]);
}

// 16 independent 256-pt FFTs (SoA in LDS, line stride LSTR, natural order in/out).
// Thread t: line t>>4, lane t&15.
template<int SIGN>
__device__ void fft256x16_t(float* RE, float* IM, int tid) {
    const int line = tid >> 4, lane = tid & 15;
    float* re = RE + line * LSTR;
    float* im = IM + line * LSTR;
    __syncthreads();                       // staging visibility
    float vr[16], vi[16];
    #pragma unroll
    for (int m = 0; m < 16; m++) { vr[m] = re[16*m + lane]; vi[m] = im[16*m + lane]; }
    dft16<SIGN>(vr, vi);
    float stepi, stepr;
    __sincosf((float)SIGN * 0.0245436926066f * (float)lane, &stepi, &stepr);
    float wr = stepr, wi = stepi;
    #pragma unroll
    for (int k1 = 1; k1 < 16; k1++) {
        int s = ((k1 & 3) << 2) | (k1 >> 2);
        float ar = vr[s], ai = vi[s];
        vr[s] = ar * wr - ai * wi; vi[s] = ar * wi + ai * wr;
        float nr = wr * stepr - wi * stepi, ni = wr * stepi + wi * stepr;
        wr = nr; wi = ni;
    }
    #pragma unroll
    for (int k1 = 0; k1 < 16; k1++) {
        int s = ((k1 & 3) << 2) | (k1 >> 2);
        re[k1*16 + lane] = vr[s]; im[k1*16 + lane] = vi[s];
    }
    __syncthreads();
    #pragma unroll
    for (int n2 = 0; n2 < 16; n2++) { vr[n2] = re[lane*16 + n2]; vi[n2] = im[lane*16 + n2]; }
    dft16<SIGN>(vr, vi);
    #pragma unroll
    for (int k2 = 0; k2 < 16; k2++) {
        int s = ((k2 & 3) << 2) | (k2 >> 2);
        re[16*k2 + lane] = vr[s]; im[16*k2 + lane] = vi[s];
    }
    __syncthreads();
}

__device__ __forceinline__ void fft256x16(float* RE, float* IM, int tid, float sign) {
    if (sign < 0.0f) fft256x16_t<-1>(RE, IM, tid);
    else             fft256x16_t<1>(RE, IM, tid);
}

__device__ __forceinline__ int cell_key(float x, float y, float z) {
    int ix = (int)(x * 256.0f), iy = (int)(y * 256.0f), iz = (int)(z * 256.0f);
    return ((ix >> 3) << 9) | ((iy >> 3) << 4) | (iz >> 4);
}

// ---- sort pass 1: histogram of cell keys ----
__global__ void k_hist(const float* __restrict__ V, int* __restrict__ cnt) {
    int i = blockIdx.x * blockDim.x + threadIdx.x;
    if (i >= NPTS) return;
    atomicAdd(&cnt[cell_key(V[3 * i], V[3 * i + 1], V[3 * i + 2])], 1);
}

// ---- sort pass 2: exclusive scan of 16384 counts (single block) ----
__global__ void k_scan(const int* __restrict__ cnt, int* __restrict__ off,
                       int* __restrict__ cnt2) {
    __shared__ int s[256];
    int t = threadIdx.x;
    int sum = 0;
    for (int j = 0; j < 64; j++) sum += cnt[t * 64 + j];
    s[t] = sum;
    __syncthreads();
    if (t == 0) { int run = 0; for (int j = 0; j < 256; j++) { int c = s[j]; s[j] = run; run += c; } }
    __syncthreads();
    int run = s[t];
    for (int j = 0; j < 64; j++) {
        int c = cnt[t * 64 + j];
        off[t * 64 + j] = run;
        cnt2[t * 64 + j] = run;
        run += c;
    }
    if (t == 255) off[NKEY] = run;   // == NPTS
}

// ---- sort pass 3 (packed): scatter coords+normals into cell order ----
__global__ void k_scatter_pk(const float* __restrict__ V, const float* __restrict__ N,
                             int* __restrict__ cnt2, float* __restrict__ Vs,
                             float* __restrict__ Nx, float* __restrict__ Ny,
                             float* __restrict__ Nz) {
    int i = blockIdx.x * blockDim.x + threadIdx.x;
    if (i >= NPTS) return;
    float x = V[3 * i], y = V[3 * i + 1], z = V[3 * i + 2];
    int s = atomicAdd(&cnt2[cell_key(x, y, z)], 1);
    Vs[3 * s] = x; Vs[3 * s + 1] = y; Vs[3 * s + 2] = z;
    Nx[s] = N[3 * i]; Ny[s] = N[3 * i + 1]; Nz[s] = N[3 * i + 2];
}

// ---- legacy sort pass 3: scatter indices (fallback path) ----
__global__ void k_scatter(const float* __restrict__ V, int* __restrict__ cnt2,
                          int* __restrict__ idx) {
    int i = blockIdx.x * blockDim.x + threadIdx.x;
    if (i >= NPTS) return;
    int s = atomicAdd(&cnt2[cell_key(V[3 * i], V[3 * i + 1], V[3 * i + 2])], 1);
    idx[s] = i;
}

// ---- dual/single-channel atomic-free rasterize, flattened work distribution.
// G1 == null -> single channel (only Na -> G0). ----
__global__ void k_rastg2(const float* __restrict__ Vs, const float* __restrict__ Na,
                         const float* __restrict__ Nb, const int* __restrict__ off,
                         float* __restrict__ G0, float* __restrict__ G1, int bOnes) {
    __shared__ float t0[1024], t1[1024];
    __shared__ int seg_s[8];
    __shared__ int seg_p[9];
    const bool dual = (G1 != 0);
    int t = threadIdx.x;
    int CZ = blockIdx.x, CY = blockIdx.y, CX = blockIdx.z;
    if (t < 8) {
        int cc = t;
        int cx = (CX - ((cc >> 2) & 1)) & 31;
        int cy = (CY - ((cc >> 1) & 1)) & 31;
        int cz = (CZ - (cc & 1)) & 15;
        int key = (cx << 9) | (cy << 4) | cz;
        int s = off[key];
        seg_s[t] = s;
        seg_p[t + 1] = off[key + 1] - s;
    }
    #pragma unroll
    for (int q = 0; q < 4; q++) { t0[t + q * 256] = 0.0f; if (dual) t1[t + q * 256] = 0.0f; }
    __syncthreads();
    if (t == 0) {
        seg_p[0] = 0;
        #pragma unroll
        for (int j = 0; j < 8; j++) seg_p[j + 1] += seg_p[j];
    }
    __syncthreads();
    int T = seg_p[8];
    int X0 = CX << 3, Y0 = CY << 3, Z0 = CZ << 4;
    for (int w = t; w < T; w += 256) {
        int c = 0;
        #pragma unroll
        for (int j = 1; j < 8; j++) c += (w >= seg_p[j]);
        int p = seg_s[c] + (w - seg_p[c]);
        float xs = Vs[3 * p] * 256.0f, ys = Vs[3 * p + 1] * 256.0f, zs = Vs[3 * p + 2] * 256.0f;
        float va = Na[p];
        float vb = dual ? (bOnes ? 1.0f : Nb[p]) : 0.0f;
        int ix0 = (int)xs, iy0 = (int)ys, iz0 = (int)zs;
        float fx = xs - ix0, fy = ys - iy0, fz = zs - iz0;
        #pragma unroll
        for (int cb = 0; cb < 8; cb++) {
            int bx = (cb >> 2) & 1, by = (cb >> 1) & 1, bz = cb & 1;
            int lx = ((bx ? ix0 + 1 : ix0) - X0) & 255;
            int ly = ((by ? iy0 + 1 : iy0) - Y0) & 255;
            int lz = ((bz ? iz0 + 1 : iz0) - Z0) & 255;
            if (lx < 8 && ly < 8 && lz < 16) {
                float w8 = (bx ? fx : 1.0f - fx) * (by ? fy : 1.0f - fy) * (bz ? fz : 1.0f - fz);
                int li = (((lx << 3) + ly) << 4) + lz;
                atomicAdd(&t0[li], w8 * va);
                if (dual) atomicAdd(&t1[li], w8 * vb);
            }
        }
    }
    __syncthreads();
    #pragma unroll
    for (int q = 0; q < 4; q++) {
        int l = t + q * 256;
        int lx = l >> 7, ly = (l >> 4) & 7, lz = l & 15;
        size_t a = (size_t)(((X0 + lx) << 16) | ((Y0 + ly) << 8) | (Z0 + lz));
        G0[a] = t0[l];
        if (dual) G1[a] = t1[l];
    }
}

// ---- legacy rasterize via idx (fallback) ----
__global__ void k_rastg(const int* __restrict__ idx, const int* __restrict__ off,
                        const float* __restrict__ V, const float* __restrict__ N,
                        float* __restrict__ R, int d) {
    __shared__ float tile[1024];
    int t = threadIdx.x;
    #pragma unroll
    for (int q = 0; q < 4; q++) tile[t + q * 256] = 0.0f;
    __syncthreads();
    int CZ = blockIdx.x, CY = blockIdx.y, CX = blockIdx.z;
    int X0 = CX << 3, Y0 = CY << 3, Z0 = CZ << 4;
    #pragma unroll
    for (int cc = 0; cc < 8; cc++) {
        int cx = (CX - ((cc >> 2) & 1)) & 31;
        int cy = (CY - ((cc >> 1) & 1)) & 31;
        int cz = (CZ - (cc & 1)) & 15;
        int key = (cx << 9) | (cy << 4) | cz;
        int s = off[key], e = off[key + 1];
        for (int p = s + t; p < e; p += 256) {
            int i = idx[p];
            float xs = V[3 * i] * 256.0f, ys = V[3 * i + 1] * 256.0f, zs = V[3 * i + 2] * 256.0f;
            float val = N[3 * i + d];
            int ix0 = (int)xs, iy0 = (int)ys, iz0 = (int)zs;
            float fx = xs - ix0, fy = ys - iy0, fz = zs - iz0;
            #pragma unroll
            for (int c = 0; c < 8; c++) {
                int bx = (c >> 2) & 1, by = (c >> 1) & 1, bz = c & 1;
                int lx = ((bx ? ix0 + 1 : ix0) - X0) & 255;
                int ly = ((by ? iy0 + 1 : iy0) - Y0) & 255;
                int lz = ((bz ? iz0 + 1 : iz0) - Z0) & 255;
                if (lx < 8 && ly < 8 && lz < 16) {
                    float w = (bx ? fx : 1.0f - fx) * (by ? fy : 1.0f - fy) * (bz ? fz : 1.0f - fz);
                    atomicAdd(&tile[(((lx << 3) + ly) << 4) + lz], w * val);
                }
            }
        }
    }
    __syncthreads();
    #pragma unroll
    for (int q = 0; q < 4; q++) {
        int l = t + q * 256;
        int lx = l >> 7, ly = (l >> 4) & 7, lz = l & 15;
        R[(size_t)(((X0 + lx) << 16) | ((Y0 + ly) << 8) | (Z0 + lz))] = tile[l];
    }
}

// ====================================================================
// k-blocked layouts (R1-proven block-level kernels).
// A-layout:  A[x][kb][y][kl]  (kb = k>>4, kl = k&15, kb in [0,9))
// B-layout:  B[y][kb][x][kl]
// ====================================================================

// ---- forward rfft along z -> A-layout ----
__global__ void k_rfft_zA(const float* __restrict__ R, float2* __restrict__ CA) {
    __shared__ __align__(16) float RE[16 * LSTR];
    __shared__ __align__(16) float IM[16 * LSTR];
    int x = blockIdx.x, y0 = blockIdx.y * 16, tid = threadIdx.x;
    #pragma unroll
    for (int l = 0; l < 16; l++) {
        float v = R[(((size_t)x << 8) + (y0 + l)) * 256 + tid];
        RE[l * LSTR + tid] = v;
        IM[l * LSTR + tid] = 0.0f;
    }
    fft256x16(RE, IM, tid, -1.0f);
    if (tid < KH) {
        int kb = tid >> 4, kl = tid & 15;
        #pragma unroll
        for (int l = 0; l < 16; l++) {
            CA[((size_t)(x * 9 + kb) * 256 + (y0 + l)) * 16 + kl] =
                make_float2(RE[l * LSTR + tid], IM[l * LSTR + tid]);
        }
    }
}

// ---- forward FFT along y. Reads A-tile (contiguous 32KB). kb<dstKB -> B-layout
// scratch; kb>=dstKB (Nyquist group): nyqDst ? [x][y][kl] at nyqDst : in-place. ----
__global__ void k_fft_yA_f(float2* __restrict__ CA, float2* __restrict__ dstB, int dstKB,
                           float2* __restrict__ nyqDst) {
    __shared__ __align__(16) float RE[16 * LSTR];
    __shared__ __align__(16) float IM[16 * LSTR];
    int x = blockIdx.x, kb = blockIdx.y, tid = threadIdx.x;
    const float4* s4 = (const float4*)(CA + ((size_t)x * 9 + kb) * TILE);
    #pragma unroll
    for (int it = 0; it < 8; it++) {
        float4 v = s4[it * 256 + tid];
        int f2 = (it * 256 + tid) * 2;
        int y = f2 >> 4, kl = f2 & 15;
        RE[kl * LSTR + y] = v.x;       IM[kl * LSTR + y] = v.y;
        RE[(kl + 1) * LSTR + y] = v.z; IM[(kl + 1) * LSTR + y] = v.w;
    }
    fft256x16(RE, IM, tid, -1.0f);
    if (kb < dstKB) {
        float4* d4 = (float4*)(dstB + (size_t)kb * TILE + (size_t)x * 16);
        size_t ystr4 = (size_t)dstKB * TILE / 2;     // float4 stride per y
        #pragma unroll
        for (int it = 0; it < 8; it++) {
            int f2 = (it * 256 + tid) * 2;
            int y = f2 >> 4, kl = f2 & 15;
            d4[(size_t)y * ystr4 + (kl >> 1)] =
                make_float4(RE[kl * LSTR + y], IM[kl * LSTR + y],
                            RE[(kl + 1) * LSTR + y], IM[(kl + 1) * LSTR + y]);
        }
    } else {
        float4* d4 = nyqDst ? (float4*)(nyqDst + (size_t)x * TILE)
                            : (float4*)(CA + ((size_t)x * 9 + kb) * TILE);
        #pragma unroll
        for (int it = 0; it < 8; it++) {
            int f2 = (it * 256 + tid) * 2;
            int y = f2 >> 4, kl = f2 & 15;
            d4[it * 256 + tid] =
                make_float4(RE[kl * LSTR + y], IM[kl * LSTR + y],
                            RE[(kl + 1) * LSTR + y], IM[(kl + 1) * LSTR + y]);
        }
    }
}

// ---- inverse FFT along y, in-place on A-tiles (fully contiguous) ----
__global__ void k_fft_yA_i(float2* __restrict__ CA) {
    __shared__ __align__(16) float RE[16 * LSTR];
    __shared__ __align__(16) float IM[16 * LSTR];
    int x = blockIdx.x, kb = blockIdx.y, tid = threadIdx.x;
    float4* s4 = (float4*)(CA + ((size_t)x * 9 + kb) * TILE);
    #pragma unroll
    for (int it = 0; it < 8; it++) {
        float4 v = s4[it * 256 + tid];
        int f2 = (it * 256 + tid) * 2;
        int y = f2 >> 4, kl = f2 & 15;
        RE[kl * LSTR + y] = v.x;       IM[kl * LSTR + y] = v.y;
        RE[(kl + 1) * LSTR + y] = v.z; IM[(kl + 1) * LSTR + y] = v.w;
    }
    fft256x16(RE, IM, tid, 1.0f);
    #pragma unroll
    for (int it = 0; it < 8; it++) {
        int f2 = (it * 256 + tid) * 2;
        int y = f2 >> 4, kl = f2 & 15;
        s4[it * 256 + tid] =
            make_float4(RE[kl * LSTR + y], IM[kl * LSTR + y],
                        RE[(kl + 1) * LSTR + y], IM[(kl + 1) * LSTR + y]);
    }
}

// ---- fused 3-channel forward-x + spectral MAC + inverse-x -> CA.
// B1: ch1 (Nx) B9; B2: ch2 (Ny) B8 (+Ny2 Nyquist [x][y][kl]);
// B3: ch3 (Nz) B8 (+Nyquist parked in CA kb=8, read in-block before overwrite).
// __launch_bounds__(256,4): LDS already caps at 4 blocks/CU (= 4 waves/EU), so
// allow 128 VGPRs -> keeps the 32-reg spectral accumulator out of scratch. ----
__global__ void __launch_bounds__(256, 4)
k_fft_x3(const float2* __restrict__ B1, const float2* __restrict__ B2,
         const float2* __restrict__ Ny2, const float2* __restrict__ B3,
         float2* __restrict__ CA) {
    __shared__ __align__(16) float RE[16 * LSTR];
    __shared__ __align__(16) float IM[16 * LSTR];
    int y = blockIdx.x, kb = blockIdx.y, tid = threadIdx.x;
    float fy = (y < 128) ? (float)y : (float)(y - 256);
    float accr[16], acci[16];
    #pragma unroll
    for (int ch = 0; ch < 3; ch++) {
        if (ch) __syncthreads();          // prior MAC's LDS reads done before restage
        if (ch == 0) {
            const float4* s4 = (const float4*)(B1 + ((size_t)y * 9 + kb) * TILE);
            #pragma unroll
            for (int it = 0; it < 8; it++) {
                float4 v = s4[it * 256 + tid];
                int f2 = (it * 256 + tid) * 2;
                int xx = f2 >> 4, kl = f2 & 15;
                RE[kl * LSTR + xx] = v.x;       IM[kl * LSTR + xx] = v.y;
                RE[(kl + 1) * LSTR + xx] = v.z; IM[(kl + 1) * LSTR + xx] = v.w;
            }
        } else if (kb < 8) {
            const float2* Bc = (ch == 1) ? B2 : B3;
            const float4* s4 = (const float4*)(Bc + ((size_t)y * 8 + kb) * TILE);
            #pragma unroll
            for (int it = 0; it < 8; it++) {
                float4 v = s4[it * 256 + tid];
                int f2 = (it * 256 + tid) * 2;
                int xx = f2 >> 4, kl = f2 & 15;
                RE[kl * LSTR + xx] = v.x;       IM[kl * LSTR + xx] = v.y;
                RE[(kl + 1) * LSTR + xx] = v.z; IM[(kl + 1) * LSTR + xx] = v.w;
            }
        } else if (ch == 1) {             // ch2 Nyquist from pack ([x][y][kl])
            const float4* c4 = (const float4*)Ny2;
            #pragma unroll
            for (int it = 0; it < 8; it++) {
                int f2 = (it * 256 + tid) * 2;
                int xx = f2 >> 4, kl = f2 & 15;
                float4 v = c4[(size_t)xx * 2048 + y * 8 + (kl >> 1)];
                RE[kl * LSTR + xx] = v.x;       IM[kl * LSTR + xx] = v.y;
                RE[(kl + 1) * LSTR + xx] = v.z; IM[(kl + 1) * LSTR + xx] = v.w;
            }
        } else {                          // ch3 Nyquist from CA kb=8 A-tiles
            const float4* c4 = (const float4*)CA;
            #pragma unroll
            for (int it = 0; it < 8; it++) {
                int f2 = (it * 256 + tid) * 2;
                int xx = f2 >> 4, kl = f2 & 15;
                float4 v = c4[(((size_t)(xx * 9 + 8) * 256 + y) * 16 + kl) >> 1];
                RE[kl * LSTR + xx] = v.x;       IM[kl * LSTR + xx] = v.y;
                RE[(kl + 1) * LSTR + xx] = v.z; IM[(kl + 1) * LSTR + xx] = v.w;
            }
        }
        fft256x16(RE, IM, tid, -1.0f);
        #pragma unroll
        for (int it = 0; it < 16; it++) {
            int f = it * 256 + tid;
            int xx = f >> 4, kl = f & 15;
            int k = kb * 16 + kl;
            float fx = (xx < 128) ? (float)xx : (float)(xx - 256);
            float f2v = fx * fx + fy * fy + (float)(k * k);
            float G = __expf(-0.0030517578125f * f2v);   // exp(-0.5*(2*SIG*|f|/256)^2)
            float fd = (ch == 0) ? fx : ((ch == 1) ? fy : (float)k);
            float s = G * (6.283185307179586f * fd) / (1e-6f - 39.47841760435743f * f2v);
            float xr = RE[kl * LSTR + xx], xi = IM[kl * LSTR + xx];
            if (ch == 0) { accr[it] = s * xi;  acci[it] = -s * xr; }
            else         { accr[it] += s * xi; acci[it] -= s * xr; }
        }
    }
    __syncthreads();                       // MAC reads done before acc restage
    #pragma unroll
    for (int it = 0; it < 16; it++) {
        int f = it * 256 + tid;
        int xx = f >> 4, kl = f & 15;
        RE[kl * LSTR + xx] = accr[it];
        IM[kl * LSTR + xx] = acci[it];
    }
    fft256x16(RE, IM, tid, 1.0f);
    float4* c4w = (float4*)CA;
    #pragma unroll
    for (int it = 0; it < 8; it++) {
        int f2 = (it * 256 + tid) * 2;
        int xx = f2 >> 4, kl = f2 & 15;
        c4w[(((size_t)(xx * 9 + kb) * 256 + y) * 16 + kl) >> 1] =
            make_float4(RE[kl * LSTR + xx], IM[kl * LSTR + xx],
                        RE[(kl + 1) * LSTR + xx], IM[(kl + 1) * LSTR + xx]);
    }
}

// ---- inverse rfft along z from A-layout; optional fused dot(W, phi) ----
__global__ void k_irfft_zA(const float2* __restrict__ CA, float* out,
                           const float* W, float* __restrict__ S, int fuse) {
    __shared__ __align__(16) float RE[16 * LSTR];
    __shared__ __align__(16) float IM[16 * LSTR];
    __shared__ float red[4];
    int x = blockIdx.x, y0 = blockIdx.y * 16, tid = threadIdx.x;
    {
        int n = tid;
        int k = (n <= 128) ? n : 256 - n;
        size_t koff = ((size_t)(x * 9 + (k >> 4)) * 256) * 16 + (k & 15);
        #pragma unroll
        for (int l = 0; l < 16; l++) {
            float2 v = CA[koff + (size_t)(y0 + l) * 16];
            RE[l * LSTR + n] = v.x;
            IM[l * LSTR + n] = (n <= 128) ? v.y : -v.y;
        }
    }
    fft256x16(RE, IM, tid, 1.0f);
    const float sc = 1.0f / 16777216.0f;
    float acc = 0.0f;
    #pragma unroll
    for (int l = 0; l < 16; l++) {
        size_t a = (((size_t)x << 8) + (y0 + l)) * 256 + tid;
        float v = RE[l * LSTR + tid] * sc;
        if (fuse) {
            float wv = W[a];
            acc += v * wv;
        }
        out[a] = v;
    }
    if (fuse) {
        #pragma unroll
        for (int o = 32; o > 0; o >>= 1) acc += __shfl_down(acc, o, 64);
        if ((tid & 63) == 0) red[tid >> 6] = acc;
        __syncthreads();
        if (tid == 0) atomicAdd(S, red[0] + red[1] + red[2] + red[3]);
    }
}

// ====================================================================
// Legacy khp-row kernels (fallback when ws is small)
// ====================================================================

__global__ void k_rfft_z(const float* __restrict__ R, float2* __restrict__ C, int khp) {
    __shared__ __align__(16) float RE[16 * LSTR];
    __shared__ __align__(16) float IM[16 * LSTR];
    int x = blockIdx.x, y0 = blockIdx.y * 16, tid = threadIdx.x;
    #pragma unroll
    for (int l = 0; l < 16; l++) {
        float v = R[(((size_t)x << 8) + (y0 + l)) * 256 + tid];
        RE[l * LSTR + tid] = v;
        IM[l * LSTR + tid] = 0.0f;
    }
    fft256x16(RE, IM, tid, -1.0f);
    #pragma unroll
    for (int l = 0; l < 16; l++) {
        if (tid < KH) {
            C[(((size_t)x << 8) + (y0 + l)) * khp + tid] =
                make_float2(RE[l * LSTR + tid], IM[l * LSTR + tid]);
        }
    }
}

__global__ void k_fft_y(float2* __restrict__ C, int khp, float sign) {
    __shared__ __align__(16) float RE[16 * LSTR];
    __shared__ __align__(16) float IM[16 * LSTR];
    int x = blockIdx.x, k0 = blockIdx.y * 16, tid = threadIdx.x;
    int kl = tid & 15, k = k0 + kl;
    bool valid = (k < KH);
    float2* base = C + (size_t)x * 256 * khp + k;
    #pragma unroll
    for (int it = 0; it < 16; it++) {
        int y = (tid >> 4) + it * 16;
        float2 v = valid ? base[(size_t)y * khp] : make_float2(0.0f, 0.0f);
        RE[kl * LSTR + y] = v.x;
        IM[kl * LSTR + y] = v.y;
    }
    fft256x16(RE, IM, tid, sign);
    #pragma unroll
    for (int it = 0; it < 16; it++) {
        int y = (tid >> 4) + it * 16;
        if (valid) base[(size_t)y * khp] = make_float2(RE[kl * LSTR + y], IM[kl * LSTR + y]);
    }
}

__global__ void k_fft_x_acc(const float2* __restrict__ C, float2* __restrict__ Acc,
                            int khp, int mode, int d) {
    __shared__ __align__(16) float RE[16 * LSTR];
    __shared__ __align__(16) float IM[16 * LSTR];
    int y = blockIdx.x, k0 = blockIdx.y * 16, tid = threadIdx.x;
    int kl = tid & 15, k = k0 + kl;
    bool valid = (k < KH);
    size_t plane = (size_t)256 * khp;
    const float2* base = C + (size_t)y * khp + k;
    #pragma unroll
    for (int it = 0; it < 16; it++) {
        int n = (tid >> 4) + it * 16;
        float2 v = valid ? base[(size_t)n * plane] : make_float2(0.0f, 0.0f);
        RE[kl * LSTR + n] = v.x;
        IM[kl * LSTR + n] = v.y;
    }
    fft256x16(RE, IM, tid, -1.0f);
    float2* abase = Acc + (size_t)y * khp + k;
    float fy = (y < 128) ? (float)y : (float)(y - 256);
    float fz = (float)k;
    float vr[16], vi[16];
    #pragma unroll
    for (int it = 0; it < 16; it++) {
        int n = (tid >> 4) + it * 16;
        float fx = (n < 128) ? (float)n : (float)(n - 256);
        float f2 = fx * fx + fy * fy + fz * fz;
        float G = __expf(-0.0030517578125f * f2);
        float fd = (d == 0) ? fx : ((d == 1) ? fy : fz);
        float s = G * (6.283185307179586f * fd) / (1e-6f - 39.47841760435743f * f2);
        float xr = RE[kl * LSTR + n], xi = IM[kl * LSTR + n];
        float cr = s * xi, ci = -s * xr;
        if (mode >= 1) {
            float2 old = valid ? abase[(size_t)n * plane] : make_float2(0.0f, 0.0f);
            cr += old.x; ci += old.y;
        }
        if (mode == 2) { vr[it] = cr; vi[it] = ci; }
        else if (valid) abase[(size_t)n * plane] = make_float2(cr, ci);
    }
    if (mode == 2) {
        __syncthreads();
        #pragma unroll
        for (int it = 0; it < 16; it++) {
            int n = (tid >> 4) + it * 16;
            RE[kl * LSTR + n] = vr[it];
            IM[kl * LSTR + n] = vi[it];
        }
        fft256x16(RE, IM, tid, 1.0f);
        #pragma unroll
        for (int it = 0; it < 16; it++) {
            int n = (tid >> 4) + it * 16;
            if (valid) abase[(size_t)n * plane] =
                make_float2(RE[kl * LSTR + n], IM[kl * LSTR + n]);
        }
    }
}

__global__ void k_irfft_z(const float2* __restrict__ A, float* out, int khp,
                          const float* W, float* __restrict__ S, int fuse) {
    __shared__ __align__(16) float RE[16 * LSTR];
    __shared__ __align__(16) float IM[16 * LSTR];
    __shared__ float red[4];
    int x = blockIdx.x, y0 = blockIdx.y * 16, tid = threadIdx.x;
    #pragma unroll
    for (int l = 0; l < 16; l++) {
        const float2* src = A + (((size_t)x << 8) + (y0 + l)) * khp;
        int n = tid;
        int k = (n <= 128) ? n : 256 - n;
        float2 v = src[k];
        RE[l * LSTR + n] = v.x;
        IM[l * LSTR + n] = (n <= 128) ? v.y : -v.y;
    }
    fft256x16(RE, IM, tid, 1.0f);
    const float sc = 1.0f / 16777216.0f;
    float acc = 0.0f;
    #pragma unroll
    for (int l = 0; l < 16; l++) {
        size_t a = (((size_t)x << 8) + (y0 + l)) * 256 + tid;
        float v = RE[l * LSTR + tid] * sc;
        if (fuse) {
            float wv = W[a];
            acc += v * wv;
        }
        out[a] = v;
    }
    if (fuse) {
        #pragma unroll
        for (int o = 32; o > 0; o >>= 1) acc += __shfl_down(acc, o, 64);
        if ((tid & 63) == 0) red[tid >> 6] = acc;
        __syncthreads();
        if (tid == 0) atomicAdd(S, red[0] + red[1] + red[2] + red[3]);
    }
}

// ---- per-point trilinear interp + sum (gather; == dot(W, phi)).
// Pass the CELL-SORTED coords (Vs) so consecutive threads gather from the
// same voxel neighborhood -> L1/L2 hits instead of random 64MB misses. ----
__global__ void k_interp_sum(const float* __restrict__ phi, const float* __restrict__ V,
                             float* __restrict__ S) {
    int i = blockIdx.x * blockDim.x + threadIdx.x;
    float acc = 0.0f;
    if (i < NPTS) {
        float xs = V[3 * i + 0] * 256.0f;
        float ys = V[3 * i + 1] * 256.0f;
        float zs = V[3 * i + 2] * 256.0f;
        int ix0 = (int)floorf(xs), iy0 = (int)floorf(ys), iz0 = (int)floorf(zs);
        float fx = xs - (float)ix0, fy = ys - (float)iy0, fz = zs - (float)iz0;
        int ix1 = (ix0 + 1) & 255, iy1 = (iy0 + 1) & 255, iz1 = (iz0 + 1) & 255;
        #pragma unroll
        for (int c = 0; c < 8; c++) {
            int bx = (c >> 2) & 1, by = (c >> 1) & 1, bz = c & 1;
            int ix = bx ? ix1 : ix0, iy = by ? iy1 : iy0, iz = bz ? iz1 : iz0;
            float w = (bx ? fx : 1.0f - fx) * (by ? fy : 1.0f - fy) * (bz ? fz : 1.0f - fz);
            acc += w * phi[(((size_t)ix << 8) + (size_t)iy) * 256 + (size_t)iz];
        }
    }
    #pragma unroll
    for (int o = 32; o > 0; o >>= 1) acc += __shfl_down(acc, o, 64);
    if ((threadIdx.x & 63) == 0) atomicAdd(S, acc);
}

__global__ void k_scalars(const float* __restrict__ S, const float* __restrict__ phi,
                          float* __restrict__ sc_out) {
    float mean = S[0] * (1.0f / (float)NPTS);
    sc_out[0] = mean;
    sc_out[1] = 0.5f / fabsf(phi[0] - mean);
}

__global__ void k_scale(float* __restrict__ phi, const float* __restrict__ sc) {
    size_t i = (size_t)blockIdx.x * blockDim.x + threadIdx.x;
    float mean = sc[0], inv = sc[1];
    float4* p = (float4*)phi;
    float4 v = p[i];
    v.x = -(v.x - mean) * inv;
    v.y = -(v.y - mean) * inv;
    v.z = -(v.z - mean) * inv;
    v.w = -(v.w - mean) * inv;
    p[i] = v;
}

extern "C" void kernel_launch(void* const* d_in, const int* in_sizes, int n_in,
                              void* d_out, int out_size, void* d_ws, size_t ws_size,
                              hipStream_t stream) {
    const float* V = (const float*)d_in[0];
    const float* N = (const float*)d_in[1];
    float* out = (float*)d_out;

    const size_t RB   = 256ull * 256 * 256 * 4;               // 64 MiB
    const size_t C129 = 256ull * 256 * 129 * 8;
    const size_t C144 = 256ull * 256 * 144 * 8;               // == A/B9 tile buffer size
    const size_t SB_CNT = ((NKEY * 4 + 255) / 256) * 256;
    const size_t SB_OFF = (((NKEY + 1) * 4 + 255) / 256) * 256;
    const size_t SB_IDX = ((NPTS * 4 + 255) / 256) * 256;
    const size_t PK_VS  = ((NPTS * 3 * 4 + 255) / 256) * 256;
    const size_t PK_N   = ((NPTS * 4 + 255) / 256) * 256;
    const size_t SORT_CORE = SB_CNT * 2 + SB_OFF;             // cnt + cnt2 + off
    const size_t PACK = PK_VS + 3 * PK_N;                     // >= 8 MiB (Nyq scratch reuse)

    // mode 2 = k-blocked fused-x3 path, mode 1 = legacy packed, mode 0 = legacy idx
    int mode, khp; size_t cb;
    if      (ws_size >= RB + 2 * C144 + 256 + SORT_CORE + PACK)   { mode = 2; khp = 144; cb = C144; }
    else if (ws_size >= RB + 2 * C129 + 256 + SORT_CORE + PACK)   { mode = 1; khp = 129; cb = C129; }
    else if (ws_size >= RB + 2 * C144 + 256 + SORT_CORE + SB_IDX) { mode = 0; khp = 144; cb = C144; }
    else if (ws_size >= RB + 2 * C129 + 256 + SORT_CORE + SB_IDX) { mode = 0; khp = 129; cb = C129; }
    else return;

    char* ws = (char*)d_ws;
    float* R0   = (float*)ws;
    float2* C   = (float2*)(ws + RB);
    float2* Acc = (float2*)(ws + RB + cb);
    float*  sc  = (float*)(ws + RB + 2 * cb);                 // [0]=S, [1]=mean, [2]=inv
    char* sb = ws + RB + 2 * cb + 256;
    int* cnt  = (int*)sb;
    int* offp = (int*)(sb + SB_CNT);
    int* cnt2 = (int*)(sb + SB_CNT + SB_OFF);
    char* pb = sb + SORT_CORE;
    float* Vs  = (float*)pb;
    float* Nxp = (float*)(pb + PK_VS);
    float* Nyp = (float*)(pb + PK_VS + PK_N);
    float* Nzp = (float*)(pb + PK_VS + 2 * PK_N);
    int* idx = (int*)pb;   // legacy path reuses pack region

    hipMemsetAsync(sc, 0, 16, stream);
    hipMemsetAsync(cnt, 0, NKEY * 4, stream);

    dim3 b256(256);
    dim3 g_z(256, 16);
    dim3 g_t(256, 9);
    dim3 g_pts((NPTS + 255) / 256);
    dim3 g_cell(16, 32, 32);   // cz, cy, cx

    k_hist<<<g_pts, b256, 0, stream>>>(V, cnt);
    k_scan<<<1, b256, 0, stream>>>(cnt, offp, cnt2);

    if (mode == 2) {
        k_scatter_pk<<<g_pts, b256, 0, stream>>>(V, N, cnt2, Vs, Nxp, Nyp, Nzp);
        float2* outB = (float2*)out;
        float2* r0B  = (float2*)R0;
        float2* nyq2 = (float2*)(pb + PK_VS + PK_N);  // ch2 Nyquist scratch (Nyp/Nzp region;
                                                      // dead after last rasterize, Vs stays live)
        // rasterize walk A (dual): Nx -> R0, Ny -> out
        k_rastg2<<<g_cell, b256, 0, stream>>>(Vs, Nxp, Nyp, offp, R0, out, 0);
        // ch1 (Nx, d=0): z -> C:A, y -> Acc:B9 (all 9 kb groups)
        k_rfft_zA<<<g_z, b256, 0, stream>>>(R0, C);
        k_fft_yA_f<<<g_t, b256, 0, stream>>>(C, Acc, 9, (float2*)0);
        // rasterize walk B (single): Nz -> R0   (R0 free after ch1-z)
        k_rastg2<<<g_cell, b256, 0, stream>>>(Vs, Nzp, (const float*)0, offp, R0, (float*)0, 0);
        // ch2 (Ny, d=1): z -> C:A, y -> out:B8 + Nyq -> pack (Nyp/Nzp now dead)
        k_rfft_zA<<<g_z, b256, 0, stream>>>(out, C);
        k_fft_yA_f<<<g_t, b256, 0, stream>>>(C, outB, 8, nyq2);
        // ch3 (Nz, d=2): z -> C:A, y -> R0:B8 + Nyq in-place (CA kb=8)
        k_rfft_zA<<<g_z, b256, 0, stream>>>(R0, C);
        k_fft_yA_f<<<g_t, b256, 0, stream>>>(C, r0B, 8, (float2*)0);
        // fused: forward-x(3ch) + spectral MAC + inverse-x -> C:A
        k_fft_x3<<<g_t, b256, 0, stream>>>(Acc, outB, nyq2, r0B, C);
        // inverse y, inverse z
        k_fft_yA_i<<<g_t, b256, 0, stream>>>(C);
        k_irfft_zA<<<g_z, b256, 0, stream>>>(C, out, (const float*)0, sc, 0);
        // mean via gather-interp on SORTED coords (== dot(W, phi))
        k_interp_sum<<<g_pts, b256, 0, stream>>>(out, Vs, sc);
    } else if (mode == 1) {
        k_scatter_pk<<<g_pts, b256, 0, stream>>>(V, N, cnt2, Vs, Nxp, Nyp, Nzp);
        k_rastg2<<<g_cell, b256, 0, stream>>>(Vs, Nxp, Nyp, offp, R0, out, 0);
        k_rfft_z<<<g_z, b256, 0, stream>>>(R0, C, khp);
        k_fft_y<<<g_t, b256, 0, stream>>>(C, khp, -1.0f);
        k_fft_x_acc<<<g_t, b256, 0, stream>>>(C, Acc, khp, 0, 0);
        k_rfft_z<<<g_z, b256, 0, stream>>>(out, C, khp);
        k_fft_y<<<g_t, b256, 0, stream>>>(C, khp, -1.0f);
        k_fft_x_acc<<<g_t, b256, 0, stream>>>(C, Acc, khp, 1, 1);
        k_rastg2<<<g_cell, b256, 0, stream>>>(Vs, Nzp, (const float*)0, offp, R0, out, 1);
        k_rfft_z<<<g_z, b256, 0, stream>>>(R0, C, khp);
        k_fft_y<<<g_t, b256, 0, stream>>>(C, khp, -1.0f);
        k_fft_x_acc<<<g_t, b256, 0, stream>>>(C, Acc, khp, 2, 2);
        k_fft_y<<<g_t, b256, 0, stream>>>(Acc, khp, 1.0f);
        k_irfft_z<<<g_z, b256, 0, stream>>>(Acc, out, khp, out, sc, 1);
    } else {
        k_scatter<<<g_pts, b256, 0, stream>>>(V, cnt2, idx);
        for (int d = 0; d < 3; d++) {
            k_rastg<<<g_cell, b256, 0, stream>>>(idx, offp, V, N, R0, d);
            k_rfft_z<<<g_z, b256, 0, stream>>>(R0, C, khp);
            k_fft_y<<<g_t, b256, 0, stream>>>(C, khp, -1.0f);
            k_fft_x_acc<<<g_t, b256, 0, stream>>>(C, Acc, khp, d, d);
        }
        k_fft_y<<<g_t, b256, 0, stream>>>(Acc, khp, 1.0f);
        k_irfft_z<<<g_z, b256, 0, stream>>>(Acc, out, khp, (const float*)0, sc, 0);
        k_interp_sum<<<g_pts, b256, 0, stream>>>(out, V, sc);
    }

    k_scalars<<<1, 1, 0, stream>>>(sc, out, sc + 1);
    k_scale<<<16777216 / 4 / 256, 256, 0, stream>>>(out, sc + 1);
}

// Round 8
// 566.966 us; speedup vs baseline: 1.3707x; 1.3707x over previous
//
#include <hip/hip_runtime.h>
#include <math.h>

#define NPTS 500000
#define KH 129
#define NKEY 16384   // 32x32x16 cells of 8x8x16 voxels
#define LSTR 260     // LDS line stride (floats): 16B-aligned, breaks pow2 conflicts
#define TILE 4096    // 256*16 float2 per (x|y, kb) tile
// Spectral truncation: G = exp(-12.5*(|f|/64)^2) -> modes with kz>=64 or |fy|>=64
// carry weight <= e^-12.5 = 3.7e-6; dropping them changes phi by <~1e-3 worst case.
#define KB4 4        // kept kz groups: k in [0,64)

// ---------------- radix-16 x radix-16 register FFT ----------------
template<int SIGN>
__device__ __forceinline__ void dft4v(float& ar, float& ai, float& br, float& bi,
                                      float& cr, float& ci, float& dr, float& di) {
    float t0r = ar + cr, t0i = ai + ci;
    float t1r = ar - cr, t1i = ai - ci;
    float t2r = br + dr, t2i = bi + di;
    float t3r = br - dr, t3i = bi - di;
    ar = t0r + t2r; ai = t0i + t2i;
    cr = t0r - t2r; ci = t0i - t2i;
    if (SIGN < 0) { br = t1r + t3i; bi = t1i - t3r; dr = t1r - t3i; di = t1i + t3r; }
    else          { br = t1r - t3i; bi = t1i + t3r; dr = t1r + t3i; di = t1i - t3r; }
}

template<int SIGN>
__device__ __forceinline__ void twmul(float& r, float& i, float c, float s) {
    float s_ = (SIGN < 0) ? -s : s;
    float ar = r, ai = i;
    r = ar * c - ai * s_;
    i = ar * s_ + ai * c;
}

// 16-pt DFT, natural input v[0..15]; output X[k] lands in slot perm4(k)=((k&3)<<2)|(k>>2)
template<int SIGN>
__device__ __forceinline__ void dft16(float* vr, float* vi) {
    #pragma unroll
    for (int n2 = 0; n2 < 4; n2++)
        dft4v<SIGN>(vr[n2], vi[n2], vr[n2+4], vi[n2+4], vr[n2+8], vi[n2+8], vr[n2+12], vi[n2+12]);
    const float C1 = 0.923879532511287f, S1 = 0.382683432365090f;
    const float C2 = 0.707106781186548f, S2 = 0.707106781186548f;
    const float C3 = 0.382683432365090f, S3 = 0.923879532511287f;
    twmul<SIGN>(vr[5],  vi[5],  C1, S1);
    twmul<SIGN>(vr[6],  vi[6],  C2, S2);
    twmul<SIGN>(vr[7],  vi[7],  C3, S3);
    twmul<SIGN>(vr[9],  vi[9],  C2, S2);
    twmul<SIGN>(vr[10], vi[10], 0.0f, 1.0f);
    twmul<SIGN>(vr[11], vi[11], -C2, S2);
    twmul<SIGN>(vr[13], vi[13], C3, S3);
    twmul<SIGN>(vr[14], vi[14], -C2, S2);
    twmul<SIGN>(vr[15], vi[15], -C1, -S1);
    #pragma unroll
    for (int k1 = 0; k1 < 4; k1++)
        dft4v<SIGN>(vr[4*k1], vi[4*k1], vr[4*k1+1], vi[4*k1+1],
                    vr[4*k1+2], vi[4*k1+2], vr[4*k1+3], vi[4*k1+3]);
}

// 16 independent 256-pt FFTs (SoA in LDS, line stride LSTR, natural order in/out).
// Thread t: line t>>4, lane t&15. FORCEINLINE: callers keep live registers
// (e.g. k_fft_x3's 32-reg spectral accumulator) out of caller-save scratch.
template<int SIGN>
__device__ __forceinline__ void fft256x16_t(float* RE, float* IM, int tid) {
    const int line = tid >> 4, lane = tid & 15;
    float* re = RE + line * LSTR;
    float* im = IM + line * LSTR;
    __syncthreads();                       // staging visibility
    float vr[16], vi[16];
    #pragma unroll
    for (int m = 0; m < 16; m++) { vr[m] = re[16*m + lane]; vi[m] = im[16*m + lane]; }
    dft16<SIGN>(vr, vi);
    float stepi, stepr;
    __sincosf((float)SIGN * 0.0245436926066f * (float)lane, &stepi, &stepr);
    float wr = stepr, wi = stepi;
    #pragma unroll
    for (int k1 = 1; k1 < 16; k1++) {
        int s = ((k1 & 3) << 2) | (k1 >> 2);
        float ar = vr[s], ai = vi[s];
        vr[s] = ar * wr - ai * wi; vi[s] = ar * wi + ai * wr;
        float nr = wr * stepr - wi * stepi, ni = wr * stepi + wi * stepr;
        wr = nr; wi = ni;
    }
    #pragma unroll
    for (int k1 = 0; k1 < 16; k1++) {
        int s = ((k1 & 3) << 2) | (k1 >> 2);
        re[k1*16 + lane] = vr[s]; im[k1*16 + lane] = vi[s];
    }
    __syncthreads();
    #pragma unroll
    for (int n2 = 0; n2 < 16; n2++) { vr[n2] = re[lane*16 + n2]; vi[n2] = im[lane*16 + n2]; }
    dft16<SIGN>(vr, vi);
    #pragma unroll
    for (int k2 = 0; k2 < 16; k2++) {
        int s = ((k2 & 3) << 2) | (k2 >> 2);
        re[16*k2 + lane] = vr[s]; im[16*k2 + lane] = vi[s];
    }
    __syncthreads();
}

__device__ __forceinline__ void fft256x16(float* RE, float* IM, int tid, float sign) {
    if (sign < 0.0f) fft256x16_t<-1>(RE, IM, tid);
    else             fft256x16_t<1>(RE, IM, tid);
}

__device__ __forceinline__ int cell_key(float x, float y, float z) {
    int ix = (int)(x * 256.0f), iy = (int)(y * 256.0f), iz = (int)(z * 256.0f);
    return ((ix >> 3) << 9) | ((iy >> 3) << 4) | (iz >> 4);
}

// ---- sort pass 1: histogram of cell keys ----
__global__ void k_hist(const float* __restrict__ V, int* __restrict__ cnt) {
    int i = blockIdx.x * blockDim.x + threadIdx.x;
    if (i >= NPTS) return;
    atomicAdd(&cnt[cell_key(V[3 * i], V[3 * i + 1], V[3 * i + 2])], 1);
}

// ---- sort pass 2: exclusive scan of 16384 counts (single block) ----
__global__ void k_scan(const int* __restrict__ cnt, int* __restrict__ off,
                       int* __restrict__ cnt2) {
    __shared__ int s[256];
    int t = threadIdx.x;
    int sum = 0;
    for (int j = 0; j < 64; j++) sum += cnt[t * 64 + j];
    s[t] = sum;
    __syncthreads();
    if (t == 0) { int run = 0; for (int j = 0; j < 256; j++) { int c = s[j]; s[j] = run; run += c; } }
    __syncthreads();
    int run = s[t];
    for (int j = 0; j < 64; j++) {
        int c = cnt[t * 64 + j];
        off[t * 64 + j] = run;
        cnt2[t * 64 + j] = run;
        run += c;
    }
    if (t == 255) off[NKEY] = run;   // == NPTS
}

// ---- sort pass 3 (packed): scatter coords+normals into cell order ----
__global__ void k_scatter_pk(const float* __restrict__ V, const float* __restrict__ N,
                             int* __restrict__ cnt2, float* __restrict__ Vs,
                             float* __restrict__ Nx, float* __restrict__ Ny,
                             float* __restrict__ Nz) {
    int i = blockIdx.x * blockDim.x + threadIdx.x;
    if (i >= NPTS) return;
    float x = V[3 * i], y = V[3 * i + 1], z = V[3 * i + 2];
    int s = atomicAdd(&cnt2[cell_key(x, y, z)], 1);
    Vs[3 * s] = x; Vs[3 * s + 1] = y; Vs[3 * s + 2] = z;
    Nx[s] = N[3 * i]; Ny[s] = N[3 * i + 1]; Nz[s] = N[3 * i + 2];
}

// ---- legacy sort pass 3: scatter indices (fallback path) ----
__global__ void k_scatter(const float* __restrict__ V, int* __restrict__ cnt2,
                          int* __restrict__ idx) {
    int i = blockIdx.x * blockDim.x + threadIdx.x;
    if (i >= NPTS) return;
    int s = atomicAdd(&cnt2[cell_key(V[3 * i], V[3 * i + 1], V[3 * i + 2])], 1);
    idx[s] = i;
}

// ---- dual/single-channel atomic-free rasterize, flattened work distribution.
// G1 == null -> single channel (only Na -> G0). ----
__global__ void k_rastg2(const float* __restrict__ Vs, const float* __restrict__ Na,
                         const float* __restrict__ Nb, const int* __restrict__ off,
                         float* __restrict__ G0, float* __restrict__ G1, int bOnes) {
    __shared__ float t0[1024], t1[1024];
    __shared__ int seg_s[8];
    __shared__ int seg_p[9];
    const bool dual = (G1 != 0);
    int t = threadIdx.x;
    int CZ = blockIdx.x, CY = blockIdx.y, CX = blockIdx.z;
    if (t < 8) {
        int cc = t;
        int cx = (CX - ((cc >> 2) & 1)) & 31;
        int cy = (CY - ((cc >> 1) & 1)) & 31;
        int cz = (CZ - (cc & 1)) & 15;
        int key = (cx << 9) | (cy << 4) | cz;
        int s = off[key];
        seg_s[t] = s;
        seg_p[t + 1] = off[key + 1] - s;
    }
    #pragma unroll
    for (int q = 0; q < 4; q++) { t0[t + q * 256] = 0.0f; if (dual) t1[t + q * 256] = 0.0f; }
    __syncthreads();
    if (t == 0) {
        seg_p[0] = 0;
        #pragma unroll
        for (int j = 0; j < 8; j++) seg_p[j + 1] += seg_p[j];
    }
    __syncthreads();
    int T = seg_p[8];
    int X0 = CX << 3, Y0 = CY << 3, Z0 = CZ << 4;
    for (int w = t; w < T; w += 256) {
        int c = 0;
        #pragma unroll
        for (int j = 1; j < 8; j++) c += (w >= seg_p[j]);
        int p = seg_s[c] + (w - seg_p[c]);
        float xs = Vs[3 * p] * 256.0f, ys = Vs[3 * p + 1] * 256.0f, zs = Vs[3 * p + 2] * 256.0f;
        float va = Na[p];
        float vb = dual ? (bOnes ? 1.0f : Nb[p]) : 0.0f;
        int ix0 = (int)xs, iy0 = (int)ys, iz0 = (int)zs;
        float fx = xs - ix0, fy = ys - iy0, fz = zs - iz0;
        #pragma unroll
        for (int cb = 0; cb < 8; cb++) {
            int bx = (cb >> 2) & 1, by = (cb >> 1) & 1, bz = cb & 1;
            int lx = ((bx ? ix0 + 1 : ix0) - X0) & 255;
            int ly = ((by ? iy0 + 1 : iy0) - Y0) & 255;
            int lz = ((bz ? iz0 + 1 : iz0) - Z0) & 255;
            if (lx < 8 && ly < 8 && lz < 16) {
                float w8 = (bx ? fx : 1.0f - fx) * (by ? fy : 1.0f - fy) * (bz ? fz : 1.0f - fz);
                int li = (((lx << 3) + ly) << 4) + lz;
                atomicAdd(&t0[li], w8 * va);
                if (dual) atomicAdd(&t1[li], w8 * vb);
            }
        }
    }
    __syncthreads();
    #pragma unroll
    for (int q = 0; q < 4; q++) {
        int l = t + q * 256;
        int lx = l >> 7, ly = (l >> 4) & 7, lz = l & 15;
        size_t a = (size_t)(((X0 + lx) << 16) | ((Y0 + ly) << 8) | (Z0 + lz));
        G0[a] = t0[l];
        if (dual) G1[a] = t1[l];
    }
}

// ---- legacy rasterize via idx (fallback) ----
__global__ void k_rastg(const int* __restrict__ idx, const int* __restrict__ off,
                        const float* __restrict__ V, const float* __restrict__ N,
                        float* __restrict__ R, int d) {
    __shared__ float tile[1024];
    int t = threadIdx.x;
    #pragma unroll
    for (int q = 0; q < 4; q++) tile[t + q * 256] = 0.0f;
    __syncthreads();
    int CZ = blockIdx.x, CY = blockIdx.y, CX = blockIdx.z;
    int X0 = CX << 3, Y0 = CY << 3, Z0 = CZ << 4;
    #pragma unroll
    for (int cc = 0; cc < 8; cc++) {
        int cx = (CX - ((cc >> 2) & 1)) & 31;
        int cy = (CY - ((cc >> 1) & 1)) & 31;
        int cz = (CZ - (cc & 1)) & 15;
        int key = (cx << 9) | (cy << 4) | cz;
        int s = off[key], e = off[key + 1];
        for (int p = s + t; p < e; p += 256) {
            int i = idx[p];
            float xs = V[3 * i] * 256.0f, ys = V[3 * i + 1] * 256.0f, zs = V[3 * i + 2] * 256.0f;
            float val = N[3 * i + d];
            int ix0 = (int)xs, iy0 = (int)ys, iz0 = (int)zs;
            float fx = xs - ix0, fy = ys - iy0, fz = zs - iz0;
            #pragma unroll
            for (int c = 0; c < 8; c++) {
                int bx = (c >> 2) & 1, by = (c >> 1) & 1, bz = c & 1;
                int lx = ((bx ? ix0 + 1 : ix0) - X0) & 255;
                int ly = ((by ? iy0 + 1 : iy0) - Y0) & 255;
                int lz = ((bz ? iz0 + 1 : iz0) - Z0) & 255;
                if (lx < 8 && ly < 8 && lz < 16) {
                    float w = (bx ? fx : 1.0f - fx) * (by ? fy : 1.0f - fy) * (bz ? fz : 1.0f - fz);
                    atomicAdd(&tile[(((lx << 3) + ly) << 4) + lz], w * val);
                }
            }
        }
    }
    __syncthreads();
    #pragma unroll
    for (int q = 0; q < 4; q++) {
        int l = t + q * 256;
        int lx = l >> 7, ly = (l >> 4) & 7, lz = l & 15;
        R[(size_t)(((X0 + lx) << 16) | ((Y0 + ly) << 8) | (Z0 + lz))] = tile[l];
    }
}

// ====================================================================
// Truncated k-blocked pipeline (mode 2).
// A-layout:  A[x][kb][y][kl], kb in [0,KB4)          (33.5 MB)
// B-compact: B[yb][kb][x][kl], yb in [0,128) mapping fy bins
//            {0..63, 192..255} via yb = y<64 ? y : y-128   (16.8 MB/channel)
// ====================================================================

// ---- forward rfft along z -> truncated A-layout (k < 64 only) ----
__global__ void k_rfft_zA4(const float* __restrict__ R, float2* __restrict__ CA) {
    __shared__ __align__(16) float RE[16 * LSTR];
    __shared__ __align__(16) float IM[16 * LSTR];
    int x = blockIdx.x, y0 = blockIdx.y * 16, tid = threadIdx.x;
    #pragma unroll
    for (int l = 0; l < 16; l++) {
        float v = R[(((size_t)x << 8) + (y0 + l)) * 256 + tid];
        RE[l * LSTR + tid] = v;
        IM[l * LSTR + tid] = 0.0f;
    }
    fft256x16_t<-1>(RE, IM, tid);
    int k = tid & 63, lg = tid >> 6;      // all 256 threads write: 4 lines each
    #pragma unroll
    for (int q = 0; q < 4; q++) {
        int l = lg * 4 + q;
        CA[((size_t)(x * KB4 + (k >> 4)) * 256 + (y0 + l)) * 16 + (k & 15)] =
            make_float2(RE[l * LSTR + k], IM[l * LSTR + k]);
    }
}

// ---- forward FFT along y; write only kept fy bins to compact B ----
__global__ void k_fft_yA_f4(const float2* __restrict__ CA, float2* __restrict__ dstB) {
    __shared__ __align__(16) float RE[16 * LSTR];
    __shared__ __align__(16) float IM[16 * LSTR];
    int x = blockIdx.x, kb = blockIdx.y, tid = threadIdx.x;
    const float4* s4 = (const float4*)(CA + ((size_t)x * KB4 + kb) * TILE);
    #pragma unroll
    for (int it = 0; it < 8; it++) {
        float4 v = s4[it * 256 + tid];
        int f2 = (it * 256 + tid) * 2;
        int y = f2 >> 4, kl = f2 & 15;
        RE[kl * LSTR + y] = v.x;       IM[kl * LSTR + y] = v.y;
        RE[(kl + 1) * LSTR + y] = v.z; IM[(kl + 1) * LSTR + y] = v.w;
    }
    fft256x16_t<-1>(RE, IM, tid);
    float4* d4 = (float4*)dstB;
    #pragma unroll
    for (int it = 0; it < 8; it++) {
        int f2 = (it * 256 + tid) * 2;
        int y = f2 >> 4, kl = f2 & 15;
        if (y < 64 || y >= 192) {         // |fy| < 64 kept
            int yb = (y < 64) ? y : y - 128;
            d4[(size_t)(yb * KB4 + kb) * 2048 + x * 8 + (kl >> 1)] =
                make_float4(RE[kl * LSTR + y], IM[kl * LSTR + y],
                            RE[(kl + 1) * LSTR + y], IM[(kl + 1) * LSTR + y]);
        }
    }
}

// ---- fused 3-channel forward-x + spectral MAC + inverse-x -> CA A-rows.
// Uniform compact-B inputs; register accumulator stays in VGPRs (inlined FFT). ----
__global__ void __launch_bounds__(256, 4)
k_fft_x3(const float2* __restrict__ B1, const float2* __restrict__ B2,
         const float2* __restrict__ B3, float2* __restrict__ CA) {
    __shared__ __align__(16) float RE[16 * LSTR];
    __shared__ __align__(16) float IM[16 * LSTR];
    int yb = blockIdx.x, kb = blockIdx.y, tid = threadIdx.x;
    int yact = (yb < 64) ? yb : yb + 128;
    float fy = (yb < 64) ? (float)yb : (float)(yb - 128);
    float accr[16], acci[16];
    #pragma unroll
    for (int ch = 0; ch < 3; ch++) {
        if (ch) __syncthreads();          // prior MAC's LDS reads done before restage
        const float2* B = (ch == 0) ? B1 : (ch == 1) ? B2 : B3;
        const float4* s4 = (const float4*)(B + (size_t)(yb * KB4 + kb) * TILE);
        #pragma unroll
        for (int it = 0; it < 8; it++) {
            float4 v = s4[it * 256 + tid];
            int f2 = (it * 256 + tid) * 2;
            int xx = f2 >> 4, kl = f2 & 15;
            RE[kl * LSTR + xx] = v.x;       IM[kl * LSTR + xx] = v.y;
            RE[(kl + 1) * LSTR + xx] = v.z; IM[(kl + 1) * LSTR + xx] = v.w;
        }
        fft256x16_t<-1>(RE, IM, tid);
        #pragma unroll
        for (int it = 0; it < 16; it++) {
            int f = it * 256 + tid;
            int xx = f >> 4, kl = f & 15;
            int k = kb * 16 + kl;
            float fx = (xx < 128) ? (float)xx : (float)(xx - 256);
            float f2v = fx * fx + fy * fy + (float)(k * k);
            float G = __expf(-0.0030517578125f * f2v);   // exp(-0.5*(2*SIG*|f|/256)^2)
            float fd = (ch == 0) ? fx : ((ch == 1) ? fy : (float)k);
            float s = G * (6.283185307179586f * fd) / (1e-6f - 39.47841760435743f * f2v);
            float xr = RE[kl * LSTR + xx], xi = IM[kl * LSTR + xx];
            if (ch == 0) { accr[it] = s * xi;  acci[it] = -s * xr; }
            else         { accr[it] += s * xi; acci[it] -= s * xr; }
        }
    }
    __syncthreads();                       // MAC reads done before acc restage
    #pragma unroll
    for (int it = 0; it < 16; it++) {
        int f = it * 256 + tid;
        int xx = f >> 4, kl = f & 15;
        RE[kl * LSTR + xx] = accr[it];
        IM[kl * LSTR + xx] = acci[it];
    }
    fft256x16_t<1>(RE, IM, tid);
    float4* c4w = (float4*)CA;
    #pragma unroll
    for (int it = 0; it < 8; it++) {
        int f2 = (it * 256 + tid) * 2;
        int xx = f2 >> 4, kl = f2 & 15;
        c4w[(((size_t)(xx * KB4 + kb) * 256 + yact) * 16 + kl) >> 1] =
            make_float4(RE[kl * LSTR + xx], IM[kl * LSTR + xx],
                        RE[(kl + 1) * LSTR + xx], IM[(kl + 1) * LSTR + xx]);
    }
}

// ---- inverse FFT along y, in-place on A-tiles; untouched (|fy|>=64) rows are
// stale from the forward pass -> staged as zero. ----
__global__ void k_fft_yA_i4(float2* __restrict__ CA) {
    __shared__ __align__(16) float RE[16 * LSTR];
    __shared__ __align__(16) float IM[16 * LSTR];
    int x = blockIdx.x, kb = blockIdx.y, tid = threadIdx.x;
    float4* s4 = (float4*)(CA + ((size_t)x * KB4 + kb) * TILE);
    #pragma unroll
    for (int it = 0; it < 8; it++) {
        int f2 = (it * 256 + tid) * 2;
        int y = f2 >> 4, kl = f2 & 15;
        bool live = (y < 64) || (y >= 192);
        float4 v = live ? s4[it * 256 + tid] : make_float4(0.0f, 0.0f, 0.0f, 0.0f);
        RE[kl * LSTR + y] = v.x;       IM[kl * LSTR + y] = v.y;
        RE[(kl + 1) * LSTR + y] = v.z; IM[(kl + 1) * LSTR + y] = v.w;
    }
    fft256x16_t<1>(RE, IM, tid);
    #pragma unroll
    for (int it = 0; it < 8; it++) {
        int f2 = (it * 256 + tid) * 2;
        int y = f2 >> 4, kl = f2 & 15;
        s4[it * 256 + tid] =
            make_float4(RE[kl * LSTR + y], IM[kl * LSTR + y],
                        RE[(kl + 1) * LSTR + y], IM[(kl + 1) * LSTR + y]);
    }
}

// ---- inverse rfft along z from truncated A-layout (k>=64 modes are zero) ----
__global__ void k_irfft_zA4(const float2* __restrict__ CA, float* __restrict__ out) {
    __shared__ __align__(16) float RE[16 * LSTR];
    __shared__ __align__(16) float IM[16 * LSTR];
    int x = blockIdx.x, y0 = blockIdx.y * 16, tid = threadIdx.x;
    {
        int n = tid;
        int k = (n <= 128) ? n : 256 - n;
        bool live = (k < 64);
        size_t koff = live ? ((size_t)(x * KB4 + (k >> 4)) * 256) * 16 + (k & 15) : 0;
        #pragma unroll
        for (int l = 0; l < 16; l++) {
            float2 v = live ? CA[koff + (size_t)(y0 + l) * 16] : make_float2(0.0f, 0.0f);
            RE[l * LSTR + n] = v.x;
            IM[l * LSTR + n] = (n <= 128) ? v.y : -v.y;
        }
    }
    fft256x16_t<1>(RE, IM, tid);
    const float sc = 1.0f / 16777216.0f;
    #pragma unroll
    for (int l = 0; l < 16; l++) {
        size_t a = (((size_t)x << 8) + (y0 + l)) * 256 + tid;
        out[a] = RE[l * LSTR + tid] * sc;
    }
}

// ====================================================================
// Legacy khp-row kernels (fallback when ws is small)
// ====================================================================

__global__ void k_rfft_z(const float* __restrict__ R, float2* __restrict__ C, int khp) {
    __shared__ __align__(16) float RE[16 * LSTR];
    __shared__ __align__(16) float IM[16 * LSTR];
    int x = blockIdx.x, y0 = blockIdx.y * 16, tid = threadIdx.x;
    #pragma unroll
    for (int l = 0; l < 16; l++) {
        float v = R[(((size_t)x << 8) + (y0 + l)) * 256 + tid];
        RE[l * LSTR + tid] = v;
        IM[l * LSTR + tid] = 0.0f;
    }
    fft256x16(RE, IM, tid, -1.0f);
    #pragma unroll
    for (int l = 0; l < 16; l++) {
        if (tid < KH) {
            C[(((size_t)x << 8) + (y0 + l)) * khp + tid] =
                make_float2(RE[l * LSTR + tid], IM[l * LSTR + tid]);
        }
    }
}

__global__ void k_fft_y(float2* __restrict__ C, int khp, float sign) {
    __shared__ __align__(16) float RE[16 * LSTR];
    __shared__ __align__(16) float IM[16 * LSTR];
    int x = blockIdx.x, k0 = blockIdx.y * 16, tid = threadIdx.x;
    int kl = tid & 15, k = k0 + kl;
    bool valid = (k < KH);
    float2* base = C + (size_t)x * 256 * khp + k;
    #pragma unroll
    for (int it = 0; it < 16; it++) {
        int y = (tid >> 4) + it * 16;
        float2 v = valid ? base[(size_t)y * khp] : make_float2(0.0f, 0.0f);
        RE[kl * LSTR + y] = v.x;
        IM[kl * LSTR + y] = v.y;
    }
    fft256x16(RE, IM, tid, sign);
    #pragma unroll
    for (int it = 0; it < 16; it++) {
        int y = (tid >> 4) + it * 16;
        if (valid) base[(size_t)y * khp] = make_float2(RE[kl * LSTR + y], IM[kl * LSTR + y]);
    }
}

__global__ void k_fft_x_acc(const float2* __restrict__ C, float2* __restrict__ Acc,
                            int khp, int mode, int d) {
    __shared__ __align__(16) float RE[16 * LSTR];
    __shared__ __align__(16) float IM[16 * LSTR];
    int y = blockIdx.x, k0 = blockIdx.y * 16, tid = threadIdx.x;
    int kl = tid & 15, k = k0 + kl;
    bool valid = (k < KH);
    size_t plane = (size_t)256 * khp;
    const float2* base = C + (size_t)y * khp + k;
    #pragma unroll
    for (int it = 0; it < 16; it++) {
        int n = (tid >> 4) + it * 16;
        float2 v = valid ? base[(size_t)n * plane] : make_float2(0.0f, 0.0f);
        RE[kl * LSTR + n] = v.x;
        IM[kl * LSTR + n] = v.y;
    }
    fft256x16(RE, IM, tid, -1.0f);
    float2* abase = Acc + (size_t)y * khp + k;
    float fy = (y < 128) ? (float)y : (float)(y - 256);
    float fz = (float)k;
    float vr[16], vi[16];
    #pragma unroll
    for (int it = 0; it < 16; it++) {
        int n = (tid >> 4) + it * 16;
        float fx = (n < 128) ? (float)n : (float)(n - 256);
        float f2 = fx * fx + fy * fy + fz * fz;
        float G = __expf(-0.0030517578125f * f2);
        float fd = (d == 0) ? fx : ((d == 1) ? fy : fz);
        float s = G * (6.283185307179586f * fd) / (1e-6f - 39.47841760435743f * f2);
        float xr = RE[kl * LSTR + n], xi = IM[kl * LSTR + n];
        float cr = s * xi, ci = -s * xr;
        if (mode >= 1) {
            float2 old = valid ? abase[(size_t)n * plane] : make_float2(0.0f, 0.0f);
            cr += old.x; ci += old.y;
        }
        if (mode == 2) { vr[it] = cr; vi[it] = ci; }
        else if (valid) abase[(size_t)n * plane] = make_float2(cr, ci);
    }
    if (mode == 2) {
        __syncthreads();
        #pragma unroll
        for (int it = 0; it < 16; it++) {
            int n = (tid >> 4) + it * 16;
            RE[kl * LSTR + n] = vr[it];
            IM[kl * LSTR + n] = vi[it];
        }
        fft256x16(RE, IM, tid, 1.0f);
        #pragma unroll
        for (int it = 0; it < 16; it++) {
            int n = (tid >> 4) + it * 16;
            if (valid) abase[(size_t)n * plane] =
                make_float2(RE[kl * LSTR + n], IM[kl * LSTR + n]);
        }
    }
}

__global__ void k_irfft_z(const float2* __restrict__ A, float* out, int khp,
                          const float* W, float* __restrict__ S, int fuse) {
    __shared__ __align__(16) float RE[16 * LSTR];
    __shared__ __align__(16) float IM[16 * LSTR];
    __shared__ float red[4];
    int x = blockIdx.x, y0 = blockIdx.y * 16, tid = threadIdx.x;
    #pragma unroll
    for (int l = 0; l < 16; l++) {
        const float2* src = A + (((size_t)x << 8) + (y0 + l)) * khp;
        int n = tid;
        int k = (n <= 128) ? n : 256 - n;
        float2 v = src[k];
        RE[l * LSTR + n] = v.x;
        IM[l * LSTR + n] = (n <= 128) ? v.y : -v.y;
    }
    fft256x16(RE, IM, tid, 1.0f);
    const float sc = 1.0f / 16777216.0f;
    float acc = 0.0f;
    #pragma unroll
    for (int l = 0; l < 16; l++) {
        size_t a = (((size_t)x << 8) + (y0 + l)) * 256 + tid;
        float v = RE[l * LSTR + tid] * sc;
        if (fuse) {
            float wv = W[a];
            acc += v * wv;
        }
        out[a] = v;
    }
    if (fuse) {
        #pragma unroll
        for (int o = 32; o > 0; o >>= 1) acc += __shfl_down(acc, o, 64);
        if ((tid & 63) == 0) red[tid >> 6] = acc;
        __syncthreads();
        if (tid == 0) atomicAdd(S, red[0] + red[1] + red[2] + red[3]);
    }
}

// ---- per-point trilinear interp + sum (gather; == dot(W, phi)) ----
__global__ void k_interp_sum(const float* __restrict__ phi, const float* __restrict__ V,
                             float* __restrict__ S) {
    int i = blockIdx.x * blockDim.x + threadIdx.x;
    float acc = 0.0f;
    if (i < NPTS) {
        float xs = V[3 * i + 0] * 256.0f;
        float ys = V[3 * i + 1] * 256.0f;
        float zs = V[3 * i + 2] * 256.0f;
        int ix0 = (int)floorf(xs), iy0 = (int)floorf(ys), iz0 = (int)floorf(zs);
        float fx = xs - (float)ix0, fy = ys - (float)iy0, fz = zs - (float)iz0;
        int ix1 = (ix0 + 1) & 255, iy1 = (iy0 + 1) & 255, iz1 = (iz0 + 1) & 255;
        #pragma unroll
        for (int c = 0; c < 8; c++) {
            int bx = (c >> 2) & 1, by = (c >> 1) & 1, bz = c & 1;
            int ix = bx ? ix1 : ix0, iy = by ? iy1 : iy0, iz = bz ? iz1 : iz0;
            float w = (bx ? fx : 1.0f - fx) * (by ? fy : 1.0f - fy) * (bz ? fz : 1.0f - fz);
            acc += w * phi[(((size_t)ix << 8) + (size_t)iy) * 256 + (size_t)iz];
        }
    }
    #pragma unroll
    for (int o = 32; o > 0; o >>= 1) acc += __shfl_down(acc, o, 64);
    if ((threadIdx.x & 63) == 0) atomicAdd(S, acc);
}

__global__ void k_scalars(const float* __restrict__ S, const float* __restrict__ phi,
                          float* __restrict__ sc_out) {
    float mean = S[0] * (1.0f / (float)NPTS);
    sc_out[0] = mean;
    sc_out[1] = 0.5f / fabsf(phi[0] - mean);
}

__global__ void k_scale(float* __restrict__ phi, const float* __restrict__ sc) {
    size_t i = (size_t)blockIdx.x * blockDim.x + threadIdx.x;
    float mean = sc[0], inv = sc[1];
    float4* p = (float4*)phi;
    float4 v = p[i];
    v.x = -(v.x - mean) * inv;
    v.y = -(v.y - mean) * inv;
    v.z = -(v.z - mean) * inv;
    v.w = -(v.w - mean) * inv;
    p[i] = v;
}

extern "C" void kernel_launch(void* const* d_in, const int* in_sizes, int n_in,
                              void* d_out, int out_size, void* d_ws, size_t ws_size,
                              hipStream_t stream) {
    const float* V = (const float*)d_in[0];
    const float* N = (const float*)d_in[1];
    float* out = (float*)d_out;

    const size_t RB   = 256ull * 256 * 256 * 4;               // 64 MiB
    const size_t C129 = 256ull * 256 * 129 * 8;
    const size_t C144 = 256ull * 256 * 144 * 8;
    const size_t SB_CNT = ((NKEY * 4 + 255) / 256) * 256;
    const size_t SB_OFF = (((NKEY + 1) * 4 + 255) / 256) * 256;
    const size_t SB_IDX = ((NPTS * 4 + 255) / 256) * 256;
    const size_t PK_VS  = ((NPTS * 3 * 4 + 255) / 256) * 256;
    const size_t PK_N   = ((NPTS * 4 + 255) / 256) * 256;
    const size_t SORT_CORE = SB_CNT * 2 + SB_OFF;             // cnt + cnt2 + off
    const size_t PACK = PK_VS + 3 * PK_N;

    // mode 2 = truncated tiled path, mode 1 = legacy packed, mode 0 = legacy idx
    int mode, khp; size_t cb;
    if      (ws_size >= RB + 2 * C144 + 256 + SORT_CORE + PACK)   { mode = 2; khp = 144; cb = C144; }
    else if (ws_size >= RB + 2 * C129 + 256 + SORT_CORE + PACK)   { mode = 1; khp = 129; cb = C129; }
    else if (ws_size >= RB + 2 * C144 + 256 + SORT_CORE + SB_IDX) { mode = 0; khp = 144; cb = C144; }
    else if (ws_size >= RB + 2 * C129 + 256 + SORT_CORE + SB_IDX) { mode = 0; khp = 129; cb = C129; }
    else return;

    char* ws = (char*)d_ws;
    float* R0   = (float*)ws;
    float2* C   = (float2*)(ws + RB);
    float2* Acc = (float2*)(ws + RB + cb);
    float*  sc  = (float*)(ws + RB + 2 * cb);                 // [0]=S, [1]=mean, [2]=inv
    char* sb = ws + RB + 2 * cb + 256;
    int* cnt  = (int*)sb;
    int* offp = (int*)(sb + SB_CNT);
    int* cnt2 = (int*)(sb + SB_CNT + SB_OFF);
    char* pb = sb + SORT_CORE;
    float* Vs  = (float*)pb;
    float* Nxp = (float*)(pb + PK_VS);
    float* Nyp = (float*)(pb + PK_VS + PK_N);
    float* Nzp = (float*)(pb + PK_VS + 2 * PK_N);
    int* idx = (int*)pb;   // legacy path reuses pack region

    hipMemsetAsync(sc, 0, 16, stream);
    hipMemsetAsync(cnt, 0, NKEY * 4, stream);

    dim3 b256(256);
    dim3 g_z(256, 16);
    dim3 g_t(256, 9);
    dim3 g_z4(256, 16);
    dim3 g_t4(256, KB4);       // (x | fy-bin, kb)
    dim3 g_x3(128, KB4);       // (yb, kb)
    dim3 g_pts((NPTS + 255) / 256);
    dim3 g_cell(16, 32, 32);   // cz, cy, cx

    k_hist<<<g_pts, b256, 0, stream>>>(V, cnt);
    k_scan<<<1, b256, 0, stream>>>(cnt, offp, cnt2);

    if (mode == 2) {
        k_scatter_pk<<<g_pts, b256, 0, stream>>>(V, N, cnt2, Vs, Nxp, Nyp, Nzp);
        float2* B1 = Acc;              // ch1 compact B (16.8 MB of 75.5)
        float2* B2 = (float2*)out;     // ch2 compact B (front of out; raster consumed first)
        float2* B3 = (float2*)R0;      // ch3 compact B (front of R0; raster consumed first)
        // rasterize walk A (dual): Nx -> R0, Ny -> out
        k_rastg2<<<g_cell, b256, 0, stream>>>(Vs, Nxp, Nyp, offp, R0, out, 0);
        // ch1 (Nx): z -> C:A4, y -> B1
        k_rfft_zA4<<<g_z4, b256, 0, stream>>>(R0, C);
        k_fft_yA_f4<<<g_t4, b256, 0, stream>>>(C, B1);
        // rasterize walk B (single): Nz -> R0 (R0 free after ch1 z-pass)
        k_rastg2<<<g_cell, b256, 0, stream>>>(Vs, Nzp, (const float*)0, offp, R0, (float*)0, 0);
        // ch2 (Ny): z -> C:A4, y -> B2 (overwrites out's raster after z consumed it)
        k_rfft_zA4<<<g_z4, b256, 0, stream>>>(out, C);
        k_fft_yA_f4<<<g_t4, b256, 0, stream>>>(C, B2);
        // ch3 (Nz): z -> C:A4, y -> B3 (overwrites R0's raster after z consumed it)
        k_rfft_zA4<<<g_z4, b256, 0, stream>>>(R0, C);
        k_fft_yA_f4<<<g_t4, b256, 0, stream>>>(C, B3);
        // fused forward-x(3ch) + spectral MAC + inverse-x -> C:A4 kept-fy rows
        k_fft_x3<<<g_x3, b256, 0, stream>>>(B1, B2, B3, C);
        // inverse y (zero-fills dropped fy rows), inverse z
        k_fft_yA_i4<<<g_t4, b256, 0, stream>>>(C);
        k_irfft_zA4<<<g_z4, b256, 0, stream>>>(C, out);
        // mean via gather-interp on sorted coords (== dot(W, phi))
        k_interp_sum<<<g_pts, b256, 0, stream>>>(out, Vs, sc);
    } else if (mode == 1) {
        k_scatter_pk<<<g_pts, b256, 0, stream>>>(V, N, cnt2, Vs, Nxp, Nyp, Nzp);
        k_rastg2<<<g_cell, b256, 0, stream>>>(Vs, Nxp, Nyp, offp, R0, out, 0);
        k_rfft_z<<<g_z, b256, 0, stream>>>(R0, C, khp);
        k_fft_y<<<g_t, b256, 0, stream>>>(C, khp, -1.0f);
        k_fft_x_acc<<<g_t, b256, 0, stream>>>(C, Acc, khp, 0, 0);
        k_rfft_z<<<g_z, b256, 0, stream>>>(out, C, khp);
        k_fft_y<<<g_t, b256, 0, stream>>>(C, khp, -1.0f);
        k_fft_x_acc<<<g_t, b256, 0, stream>>>(C, Acc, khp, 1, 1);
        k_rastg2<<<g_cell, b256, 0, stream>>>(Vs, Nzp, (const float*)0, offp, R0, out, 1);
        k_rfft_z<<<g_z, b256, 0, stream>>>(R0, C, khp);
        k_fft_y<<<g_t, b256, 0, stream>>>(C, khp, -1.0f);
        k_fft_x_acc<<<g_t, b256, 0, stream>>>(C, Acc, khp, 2, 2);
        k_fft_y<<<g_t, b256, 0, stream>>>(Acc, khp, 1.0f);
        k_irfft_z<<<g_z, b256, 0, stream>>>(Acc, out, khp, out, sc, 1);
    } else {
        k_scatter<<<g_pts, b256, 0, stream>>>(V, cnt2, idx);
        for (int d = 0; d < 3; d++) {
            k_rastg<<<g_cell, b256, 0, stream>>>(idx, offp, V, N, R0, d);
            k_rfft_z<<<g_z, b256, 0, stream>>>(R0, C, khp);
            k_fft_y<<<g_t, b256, 0, stream>>>(C, khp, -1.0f);
            k_fft_x_acc<<<g_t, b256, 0, stream>>>(C, Acc, khp, d, d);
        }
        k_fft_y<<<g_t, b256, 0, stream>>>(Acc, khp, 1.0f);
        k_irfft_z<<<g_z, b256, 0, stream>>>(Acc, out, khp, (const float*)0, sc, 0);
        k_interp_sum<<<g_pts, b256, 0, stream>>>(out, V, sc);
    }

    k_scalars<<<1, 1, 0, stream>>>(sc, out, sc + 1);
    k_scale<<<16777216 / 4 / 256, 256, 0, stream>>>(out, sc + 1);
}

// Round 10
// 484.559 us; speedup vs baseline: 1.6038x; 1.1701x over previous
//
#include <hip/hip_runtime.h>
#include <math.h>

#define NPTS 500000
#define KH 129
#define NKEY 16384   // 32x32x16 cells of 8x8x16 voxels
#define LSTR 260     // LDS line stride (floats): 16B-aligned, breaks pow2 conflicts
#define TILE 4096    // 256*16 float2 per (x|y, kb) tile
// Spectral truncation: G = exp(-12.5*(|f|/64)^2) -> modes with kz>=64 or |fy|>=64
// carry weight <= e^-12.5 = 3.7e-6; dropping them changes phi by <~1e-3 worst case.
#define KB4 4        // kept kz groups: k in [0,64)

// ---------------- radix-16 x radix-16 register FFT ----------------
template<int SIGN>
__device__ __forceinline__ void dft4v(float& ar, float& ai, float& br, float& bi,
                                      float& cr, float& ci, float& dr, float& di) {
    float t0r = ar + cr, t0i = ai + ci;
    float t1r = ar - cr, t1i = ai - ci;
    float t2r = br + dr, t2i = bi + di;
    float t3r = br - dr, t3i = bi - di;
    ar = t0r + t2r; ai = t0i + t2i;
    cr = t0r - t2r; ci = t0i - t2i;
    if (SIGN < 0) { br = t1r + t3i; bi = t1i - t3r; dr = t1r - t3i; di = t1i + t3r; }
    else          { br = t1r - t3i; bi = t1i + t3r; dr = t1r + t3i; di = t1i - t3r; }
}

template<int SIGN>
__device__ __forceinline__ void twmul(float& r, float& i, float c, float s) {
    float s_ = (SIGN < 0) ? -s : s;
    float ar = r, ai = i;
    r = ar * c - ai * s_;
    i = ar * s_ + ai * c;
}

// 16-pt DFT, natural input v[0..15]; output X[k] lands in slot perm4(k)=((k&3)<<2)|(k>>2)
template<int SIGN>
__device__ __forceinline__ void dft16(float* vr, float* vi) {
    #pragma unroll
    for (int n2 = 0; n2 < 4; n2++)
        dft4v<SIGN>(vr[n2], vi[n2], vr[n2+4], vi[n2+4], vr[n2+8], vi[n2+8], vr[n2+12], vi[n2+12]);
    const float C1 = 0.923879532511287f, S1 = 0.382683432365090f;
    const float C2 = 0.707106781186548f, S2 = 0.707106781186548f;
    const float C3 = 0.382683432365090f, S3 = 0.923879532511287f;
    twmul<SIGN>(vr[5],  vi[5],  C1, S1);
    twmul<SIGN>(vr[6],  vi[6],  C2, S2);
    twmul<SIGN>(vr[7],  vi[7],  C3, S3);
    twmul<SIGN>(vr[9],  vi[9],  C2, S2);
    twmul<SIGN>(vr[10], vi[10], 0.0f, 1.0f);
    twmul<SIGN>(vr[11], vi[11], -C2, S2);
    twmul<SIGN>(vr[13], vi[13], C3, S3);
    twmul<SIGN>(vr[14], vi[14], -C2, S2);
    twmul<SIGN>(vr[15], vi[15], -C1, -S1);
    #pragma unroll
    for (int k1 = 0; k1 < 4; k1++)
        dft4v<SIGN>(vr[4*k1], vi[4*k1], vr[4*k1+1], vi[4*k1+1],
                    vr[4*k1+2], vi[4*k1+2], vr[4*k1+3], vi[4*k1+3]);
}

// 16 independent 256-pt FFTs (SoA in LDS, line stride LSTR, natural order in/out).
// Thread t: line t>>4, lane t&15. FORCEINLINE: callers keep live registers
// (e.g. k_fft_x3's 32-reg spectral accumulator) out of caller-save scratch.
template<int SIGN>
__device__ __forceinline__ void fft256x16_t(float* RE, float* IM, int tid) {
    const int line = tid >> 4, lane = tid & 15;
    float* re = RE + line * LSTR;
    float* im = IM + line * LSTR;
    __syncthreads();                       // staging visibility
    float vr[16], vi[16];
    #pragma unroll
    for (int m = 0; m < 16; m++) { vr[m] = re[16*m + lane]; vi[m] = im[16*m + lane]; }
    dft16<SIGN>(vr, vi);
    float stepi, stepr;
    __sincosf((float)SIGN * 0.0245436926066f * (float)lane, &stepi, &stepr);
    float wr = stepr, wi = stepi;
    #pragma unroll
    for (int k1 = 1; k1 < 16; k1++) {
        int s = ((k1 & 3) << 2) | (k1 >> 2);
        float ar = vr[s], ai = vi[s];
        vr[s] = ar * wr - ai * wi; vi[s] = ar * wi + ai * wr;
        float nr = wr * stepr - wi * stepi, ni = wr * stepi + wi * stepr;
        wr = nr; wi = ni;
    }
    #pragma unroll
    for (int k1 = 0; k1 < 16; k1++) {
        int s = ((k1 & 3) << 2) | (k1 >> 2);
        re[k1*16 + lane] = vr[s]; im[k1*16 + lane] = vi[s];
    }
    __syncthreads();
    #pragma unroll
    for (int n2 = 0; n2 < 16; n2++) { vr[n2] = re[lane*16 + n2]; vi[n2] = im[lane*16 + n2]; }
    dft16<SIGN>(vr, vi);
    #pragma unroll
    for (int k2 = 0; k2 < 16; k2++) {
        int s = ((k2 & 3) << 2) | (k2 >> 2);
        re[16*k2 + lane] = vr[s]; im[16*k2 + lane] = vi[s];
    }
    __syncthreads();
}

__device__ __forceinline__ void fft256x16(float* RE, float* IM, int tid, float sign) {
    if (sign < 0.0f) fft256x16_t<-1>(RE, IM, tid);
    else             fft256x16_t<1>(RE, IM, tid);
}

__device__ __forceinline__ int cell_key(float x, float y, float z) {
    int ix = (int)(x * 256.0f), iy = (int)(y * 256.0f), iz = (int)(z * 256.0f);
    return ((ix >> 3) << 9) | ((iy >> 3) << 4) | (iz >> 4);
}

// ---- sort pass 1: histogram of cell keys ----
__global__ void k_hist(const float* __restrict__ V, int* __restrict__ cnt) {
    int i = blockIdx.x * blockDim.x + threadIdx.x;
    if (i >= NPTS) return;
    atomicAdd(&cnt[cell_key(V[3 * i], V[3 * i + 1], V[3 * i + 2])], 1);
}

// ---- sort pass 2: exclusive scan of 16384 counts (single block) ----
__global__ void k_scan(const int* __restrict__ cnt, int* __restrict__ off,
                       int* __restrict__ cnt2) {
    __shared__ int s[256];
    int t = threadIdx.x;
    int sum = 0;
    for (int j = 0; j < 64; j++) sum += cnt[t * 64 + j];
    s[t] = sum;
    __syncthreads();
    if (t == 0) { int run = 0; for (int j = 0; j < 256; j++) { int c = s[j]; s[j] = run; run += c; } }
    __syncthreads();
    int run = s[t];
    for (int j = 0; j < 64; j++) {
        int c = cnt[t * 64 + j];
        off[t * 64 + j] = run;
        cnt2[t * 64 + j] = run;
        run += c;
    }
    if (t == 255) off[NKEY] = run;   // == NPTS
}

// ---- sort pass 3 (packed): scatter coords+normals into cell order ----
__global__ void k_scatter_pk(const float* __restrict__ V, const float* __restrict__ N,
                             int* __restrict__ cnt2, float* __restrict__ Vs,
                             float* __restrict__ Nx, float* __restrict__ Ny,
                             float* __restrict__ Nz) {
    int i = blockIdx.x * blockDim.x + threadIdx.x;
    if (i >= NPTS) return;
    float x = V[3 * i], y = V[3 * i + 1], z = V[3 * i + 2];
    int s = atomicAdd(&cnt2[cell_key(x, y, z)], 1);
    Vs[3 * s] = x; Vs[3 * s + 1] = y; Vs[3 * s + 2] = z;
    Nx[s] = N[3 * i]; Ny[s] = N[3 * i + 1]; Nz[s] = N[3 * i + 2];
}

// ---- legacy sort pass 3: scatter indices (fallback path) ----
__global__ void k_scatter(const float* __restrict__ V, int* __restrict__ cnt2,
                          int* __restrict__ idx) {
    int i = blockIdx.x * blockDim.x + threadIdx.x;
    if (i >= NPTS) return;
    int s = atomicAdd(&cnt2[cell_key(V[3 * i], V[3 * i + 1], V[3 * i + 2])], 1);
    idx[s] = i;
}

// ---- dual/single-channel atomic-free rasterize, flattened work distribution.
// G1 == null -> single channel (only Na -> G0). ----
__global__ void k_rastg2(const float* __restrict__ Vs, const float* __restrict__ Na,
                         const float* __restrict__ Nb, const int* __restrict__ off,
                         float* __restrict__ G0, float* __restrict__ G1, int bOnes) {
    __shared__ float t0[1024], t1[1024];
    __shared__ int seg_s[8];
    __shared__ int seg_p[9];
    const bool dual = (G1 != 0);
    int t = threadIdx.x;
    int CZ = blockIdx.x, CY = blockIdx.y, CX = blockIdx.z;
    if (t < 8) {
        int cc = t;
        int cx = (CX - ((cc >> 2) & 1)) & 31;
        int cy = (CY - ((cc >> 1) & 1)) & 31;
        int cz = (CZ - (cc & 1)) & 15;
        int key = (cx << 9) | (cy << 4) | cz;
        int s = off[key];
        seg_s[t] = s;
        seg_p[t + 1] = off[key + 1] - s;
    }
    #pragma unroll
    for (int q = 0; q < 4; q++) { t0[t + q * 256] = 0.0f; if (dual) t1[t + q * 256] = 0.0f; }
    __syncthreads();
    if (t == 0) {
        seg_p[0] = 0;
        #pragma unroll
        for (int j = 0; j < 8; j++) seg_p[j + 1] += seg_p[j];
    }
    __syncthreads();
    int T = seg_p[8];
    int X0 = CX << 3, Y0 = CY << 3, Z0 = CZ << 4;
    for (int w = t; w < T; w += 256) {
        int c = 0;
        #pragma unroll
        for (int j = 1; j < 8; j++) c += (w >= seg_p[j]);
        int p = seg_s[c] + (w - seg_p[c]);
        float xs = Vs[3 * p] * 256.0f, ys = Vs[3 * p + 1] * 256.0f, zs = Vs[3 * p + 2] * 256.0f;
        float va = Na[p];
        float vb = dual ? (bOnes ? 1.0f : Nb[p]) : 0.0f;
        int ix0 = (int)xs, iy0 = (int)ys, iz0 = (int)zs;
        float fx = xs - ix0, fy = ys - iy0, fz = zs - iz0;
        #pragma unroll
        for (int cb = 0; cb < 8; cb++) {
            int bx = (cb >> 2) & 1, by = (cb >> 1) & 1, bz = cb & 1;
            int lx = ((bx ? ix0 + 1 : ix0) - X0) & 255;
            int ly = ((by ? iy0 + 1 : iy0) - Y0) & 255;
            int lz = ((bz ? iz0 + 1 : iz0) - Z0) & 255;
            if (lx < 8 && ly < 8 && lz < 16) {
                float w8 = (bx ? fx : 1.0f - fx) * (by ? fy : 1.0f - fy) * (bz ? fz : 1.0f - fz);
                int li = (((lx << 3) + ly) << 4) + lz;
                atomicAdd(&t0[li], w8 * va);
                if (dual) atomicAdd(&t1[li], w8 * vb);
            }
        }
    }
    __syncthreads();
    #pragma unroll
    for (int q = 0; q < 4; q++) {
        int l = t + q * 256;
        int lx = l >> 7, ly = (l >> 4) & 7, lz = l & 15;
        size_t a = (size_t)(((X0 + lx) << 16) | ((Y0 + ly) << 8) | (Z0 + lz));
        G0[a] = t0[l];
        if (dual) G1[a] = t1[l];
    }
}

// ---- legacy rasterize via idx (fallback) ----
__global__ void k_rastg(const int* __restrict__ idx, const int* __restrict__ off,
                        const float* __restrict__ V, const float* __restrict__ N,
                        float* __restrict__ R, int d) {
    __shared__ float tile[1024];
    int t = threadIdx.x;
    #pragma unroll
    for (int q = 0; q < 4; q++) tile[t + q * 256] = 0.0f;
    __syncthreads();
    int CZ = blockIdx.x, CY = blockIdx.y, CX = blockIdx.z;
    int X0 = CX << 3, Y0 = CY << 3, Z0 = CZ << 4;
    #pragma unroll
    for (int cc = 0; cc < 8; cc++) {
        int cx = (CX - ((cc >> 2) & 1)) & 31;
        int cy = (CY - ((cc >> 1) & 1)) & 31;
        int cz = (CZ - (cc & 1)) & 15;
        int key = (cx << 9) | (cy << 4) | cz;
        int s = off[key], e = off[key + 1];
        for (int p = s + t; p < e; p += 256) {
            int i = idx[p];
            float xs = V[3 * i] * 256.0f, ys = V[3 * i + 1] * 256.0f, zs = V[3 * i + 2] * 256.0f;
            float val = N[3 * i + d];
            int ix0 = (int)xs, iy0 = (int)ys, iz0 = (int)zs;
            float fx = xs - ix0, fy = ys - iy0, fz = zs - iz0;
            #pragma unroll
            for (int c = 0; c < 8; c++) {
                int bx = (c >> 2) & 1, by = (c >> 1) & 1, bz = c & 1;
                int lx = ((bx ? ix0 + 1 : ix0) - X0) & 255;
                int ly = ((by ? iy0 + 1 : iy0) - Y0) & 255;
                int lz = ((bz ? iz0 + 1 : iz0) - Z0) & 255;
                if (lx < 8 && ly < 8 && lz < 16) {
                    float w = (bx ? fx : 1.0f - fx) * (by ? fy : 1.0f - fy) * (bz ? fz : 1.0f - fz);
                    atomicAdd(&tile[(((lx << 3) + ly) << 4) + lz], w * val);
                }
            }
        }
    }
    __syncthreads();
    #pragma unroll
    for (int q = 0; q < 4; q++) {
        int l = t + q * 256;
        int lx = l >> 7, ly = (l >> 4) & 7, lz = l & 15;
        R[(size_t)(((X0 + lx) << 16) | ((Y0 + ly) << 8) | (Z0 + lz))] = tile[l];
    }
}

// ====================================================================
// Truncated k-blocked pipeline (mode 2).
// A-layout:  A[x][kb][y][kl], kb in [0,KB4)          (33.5 MB)
// B-compact: B[yb][kb][x][kl], yb in [0,128) mapping fy bins
//            {0..63, 192..255} via yb = y<64 ? y : y-128   (16.8 MB/channel)
// ====================================================================

// ---- forward rfft along z -> truncated A-layout (k < 64 only) ----
__global__ void k_rfft_zA4(const float* __restrict__ R, float2* __restrict__ CA) {
    __shared__ __align__(16) float RE[16 * LSTR];
    __shared__ __align__(16) float IM[16 * LSTR];
    int x = blockIdx.x, y0 = blockIdx.y * 16, tid = threadIdx.x;
    #pragma unroll
    for (int l = 0; l < 16; l++) {
        float v = R[(((size_t)x << 8) + (y0 + l)) * 256 + tid];
        RE[l * LSTR + tid] = v;
        IM[l * LSTR + tid] = 0.0f;
    }
    fft256x16_t<-1>(RE, IM, tid);
    int k = tid & 63, lg = tid >> 6;      // all 256 threads write: 4 lines each
    #pragma unroll
    for (int q = 0; q < 4; q++) {
        int l = lg * 4 + q;
        CA[((size_t)(x * KB4 + (k >> 4)) * 256 + (y0 + l)) * 16 + (k & 15)] =
            make_float2(RE[l * LSTR + k], IM[l * LSTR + k]);
    }
}

// ---- forward FFT along y; write only kept fy bins to compact B ----
__global__ void k_fft_yA_f4(const float2* __restrict__ CA, float2* __restrict__ dstB) {
    __shared__ __align__(16) float RE[16 * LSTR];
    __shared__ __align__(16) float IM[16 * LSTR];
    int x = blockIdx.x, kb = blockIdx.y, tid = threadIdx.x;
    const float4* s4 = (const float4*)(CA + ((size_t)x * KB4 + kb) * TILE);
    #pragma unroll
    for (int it = 0; it < 8; it++) {
        float4 v = s4[it * 256 + tid];
        int f2 = (it * 256 + tid) * 2;
        int y = f2 >> 4, kl = f2 & 15;
        RE[kl * LSTR + y] = v.x;       IM[kl * LSTR + y] = v.y;
        RE[(kl + 1) * LSTR + y] = v.z; IM[(kl + 1) * LSTR + y] = v.w;
    }
    fft256x16_t<-1>(RE, IM, tid);
    float4* d4 = (float4*)dstB;
    #pragma unroll
    for (int it = 0; it < 8; it++) {
        int f2 = (it * 256 + tid) * 2;
        int y = f2 >> 4, kl = f2 & 15;
        if (y < 64 || y >= 192) {         // |fy| < 64 kept
            int yb = (y < 64) ? y : y - 128;
            d4[(size_t)(yb * KB4 + kb) * 2048 + x * 8 + (kl >> 1)] =
                make_float4(RE[kl * LSTR + y], IM[kl * LSTR + y],
                            RE[(kl + 1) * LSTR + y], IM[(kl + 1) * LSTR + y]);
        }
    }
}

// ---- fused 3-channel forward-x + spectral MAC + inverse-x -> CA A-rows.
// Uniform compact-B inputs; register accumulator stays in VGPRs (inlined FFT). ----
__global__ void __launch_bounds__(256, 4)
k_fft_x3(const float2* __restrict__ B1, const float2* __restrict__ B2,
         const float2* __restrict__ B3, float2* __restrict__ CA) {
    __shared__ __align__(16) float RE[16 * LSTR];
    __shared__ __align__(16) float IM[16 * LSTR];
    int yb = blockIdx.x, kb = blockIdx.y, tid = threadIdx.x;
    int yact = (yb < 64) ? yb : yb + 128;
    float fy = (yb < 64) ? (float)yb : (float)(yb - 128);
    float accr[16], acci[16];
    #pragma unroll
    for (int ch = 0; ch < 3; ch++) {
        if (ch) __syncthreads();          // prior MAC's LDS reads done before restage
        const float2* B = (ch == 0) ? B1 : (ch == 1) ? B2 : B3;
        const float4* s4 = (const float4*)(B + (size_t)(yb * KB4 + kb) * TILE);
        #pragma unroll
        for (int it = 0; it < 8; it++) {
            float4 v = s4[it * 256 + tid];
            int f2 = (it * 256 + tid) * 2;
            int xx = f2 >> 4, kl = f2 & 15;
            RE[kl * LSTR + xx] = v.x;       IM[kl * LSTR + xx] = v.y;
            RE[(kl + 1) * LSTR + xx] = v.z; IM[(kl + 1) * LSTR + xx] = v.w;
        }
        fft256x16_t<-1>(RE, IM, tid);
        #pragma unroll
        for (int it = 0; it < 16; it++) {
            int f = it * 256 + tid;
            int xx = f >> 4, kl = f & 15;
            int k = kb * 16 + kl;
            float fx = (xx < 128) ? (float)xx : (float)(xx - 256);
            float f2v = fx * fx + fy * fy + (float)(k * k);
            float G = __expf(-0.0030517578125f * f2v);   // exp(-0.5*(2*SIG*|f|/256)^2)
            float fd = (ch == 0) ? fx : ((ch == 1) ? fy : (float)k);
            float s = G * (6.283185307179586f * fd) / (1e-6f - 39.47841760435743f * f2v);
            float xr = RE[kl * LSTR + xx], xi = IM[kl * LSTR + xx];
            if (ch == 0) { accr[it] = s * xi;  acci[it] = -s * xr; }
            else         { accr[it] += s * xi; acci[it] -= s * xr; }
        }
    }
    __syncthreads();                       // MAC reads done before acc restage
    #pragma unroll
    for (int it = 0; it < 16; it++) {
        int f = it * 256 + tid;
        int xx = f >> 4, kl = f & 15;
        RE[kl * LSTR + xx] = accr[it];
        IM[kl * LSTR + xx] = acci[it];
    }
    fft256x16_t<1>(RE, IM, tid);
    float4* c4w = (float4*)CA;
    #pragma unroll
    for (int it = 0; it < 8; it++) {
        int f2 = (it * 256 + tid) * 2;
        int xx = f2 >> 4, kl = f2 & 15;
        c4w[(((size_t)(xx * KB4 + kb) * 256 + yact) * 16 + kl) >> 1] =
            make_float4(RE[kl * LSTR + xx], IM[kl * LSTR + xx],
                        RE[(kl + 1) * LSTR + xx], IM[(kl + 1) * LSTR + xx]);
    }
}

// ---- inverse FFT along y, in-place on A-tiles; untouched (|fy|>=64) rows are
// stale from the forward pass -> staged as zero. ----
__global__ void k_fft_yA_i4(float2* __restrict__ CA) {
    __shared__ __align__(16) float RE[16 * LSTR];
    __shared__ __align__(16) float IM[16 * LSTR];
    int x = blockIdx.x, kb = blockIdx.y, tid = threadIdx.x;
    float4* s4 = (float4*)(CA + ((size_t)x * KB4 + kb) * TILE);
    #pragma unroll
    for (int it = 0; it < 8; it++) {
        int f2 = (it * 256 + tid) * 2;
        int y = f2 >> 4, kl = f2 & 15;
        bool live = (y < 64) || (y >= 192);
        float4 v = live ? s4[it * 256 + tid] : make_float4(0.0f, 0.0f, 0.0f, 0.0f);
        RE[kl * LSTR + y] = v.x;       IM[kl * LSTR + y] = v.y;
        RE[(kl + 1) * LSTR + y] = v.z; IM[(kl + 1) * LSTR + y] = v.w;
    }
    fft256x16_t<1>(RE, IM, tid);
    #pragma unroll
    for (int it = 0; it < 8; it++) {
        int f2 = (it * 256 + tid) * 2;
        int y = f2 >> 4, kl = f2 & 15;
        s4[it * 256 + tid] =
            make_float4(RE[kl * LSTR + y], IM[kl * LSTR + y],
                        RE[(kl + 1) * LSTR + y], IM[(kl + 1) * LSTR + y]);
    }
}

// ---- inverse rfft along z from truncated A-layout (k>=64 modes are zero) ----
__global__ void k_irfft_zA4(const float2* __restrict__ CA, float* __restrict__ out) {
    __shared__ __align__(16) float RE[16 * LSTR];
    __shared__ __align__(16) float IM[16 * LSTR];
    int x = blockIdx.x, y0 = blockIdx.y * 16, tid = threadIdx.x;
    {
        int n = tid;
        int k = (n <= 128) ? n : 256 - n;
        bool live = (k < 64);
        size_t koff = live ? ((size_t)(x * KB4 + (k >> 4)) * 256) * 16 + (k & 15) : 0;
        #pragma unroll
        for (int l = 0; l < 16; l++) {
            float2 v = live ? CA[koff + (size_t)(y0 + l) * 16] : make_float2(0.0f, 0.0f);
            RE[l * LSTR + n] = v.x;
            IM[l * LSTR + n] = (n <= 128) ? v.y : -v.y;
        }
    }
    fft256x16_t<1>(RE, IM, tid);
    const float sc = 1.0f / 16777216.0f;
    #pragma unroll
    for (int l = 0; l < 16; l++) {
        size_t a = (((size_t)x << 8) + (y0 + l)) * 256 + tid;
        out[a] = RE[l * LSTR + tid] * sc;
    }
}

// ====================================================================
// Legacy khp-row kernels (fallback when ws is small)
// ====================================================================

__global__ void k_rfft_z(const float* __restrict__ R, float2* __restrict__ C, int khp) {
    __shared__ __align__(16) float RE[16 * LSTR];
    __shared__ __align__(16) float IM[16 * LSTR];
    int x = blockIdx.x, y0 = blockIdx.y * 16, tid = threadIdx.x;
    #pragma unroll
    for (int l = 0; l < 16; l++) {
        float v = R[(((size_t)x << 8) + (y0 + l)) * 256 + tid];
        RE[l * LSTR + tid] = v;
        IM[l * LSTR + tid] = 0.0f;
    }
    fft256x16(RE, IM, tid, -1.0f);
    #pragma unroll
    for (int l = 0; l < 16; l++) {
        if (tid < KH) {
            C[(((size_t)x << 8) + (y0 + l)) * khp + tid] =
                make_float2(RE[l * LSTR + tid], IM[l * LSTR + tid]);
        }
    }
}

__global__ void k_fft_y(float2* __restrict__ C, int khp, float sign) {
    __shared__ __align__(16) float RE[16 * LSTR];
    __shared__ __align__(16) float IM[16 * LSTR];
    int x = blockIdx.x, k0 = blockIdx.y * 16, tid = threadIdx.x;
    int kl = tid & 15, k = k0 + kl;
    bool valid = (k < KH);
    float2* base = C + (size_t)x * 256 * khp + k;
    #pragma unroll
    for (int it = 0; it < 16; it++) {
        int y = (tid >> 4) + it * 16;
        float2 v = valid ? base[(size_t)y * khp] : make_float2(0.0f, 0.0f);
        RE[kl * LSTR + y] = v.x;
        IM[kl * LSTR + y] = v.y;
    }
    fft256x16(RE, IM, tid, sign);
    #pragma unroll
    for (int it = 0; it < 16; it++) {
        int y = (tid >> 4) + it * 16;
        if (valid) base[(size_t)y * khp] = make_float2(RE[kl * LSTR + y], IM[kl * LSTR + y]);
    }
}

__global__ void k_fft_x_acc(const float2* __restrict__ C, float2* __restrict__ Acc,
                            int khp, int mode, int d) {
    __shared__ __align__(16) float RE[16 * LSTR];
    __shared__ __align__(16) float IM[16 * LSTR];
    int y = blockIdx.x, k0 = blockIdx.y * 16, tid = threadIdx.x;
    int kl = tid & 15, k = k0 + kl;
    bool valid = (k < KH);
    size_t plane = (size_t)256 * khp;
    const float2* base = C + (size_t)y * khp + k;
    #pragma unroll
    for (int it = 0; it < 16; it++) {
        int n = (tid >> 4) + it * 16;
        float2 v = valid ? base[(size_t)n * plane] : make_float2(0.0f, 0.0f);
        RE[kl * LSTR + n] = v.x;
        IM[kl * LSTR + n] = v.y;
    }
    fft256x16(RE, IM, tid, -1.0f);
    float2* abase = Acc + (size_t)y * khp + k;
    float fy = (y < 128) ? (float)y : (float)(y - 256);
    float fz = (float)k;
    float vr[16], vi[16];
    #pragma unroll
    for (int it = 0; it < 16; it++) {
        int n = (tid >> 4) + it * 16;
        float fx = (n < 128) ? (float)n : (float)(n - 256);
        float f2 = fx * fx + fy * fy + fz * fz;
        float G = __expf(-0.0030517578125f * f2);
        float fd = (d == 0) ? fx : ((d == 1) ? fy : fz);
        float s = G * (6.283185307179586f * fd) / (1e-6f - 39.47841760435743f * f2);
        float xr = RE[kl * LSTR + n], xi = IM[kl * LSTR + n];
        float cr = s * xi, ci = -s * xr;
        if (mode >= 1) {
            float2 old = valid ? abase[(size_t)n * plane] : make_float2(0.0f, 0.0f);
            cr += old.x; ci += old.y;
        }
        if (mode == 2) { vr[it] = cr; vi[it] = ci; }
        else if (valid) abase[(size_t)n * plane] = make_float2(cr, ci);
    }
    if (mode == 2) {
        __syncthreads();
        #pragma unroll
        for (int it = 0; it < 16; it++) {
            int n = (tid >> 4) + it * 16;
            RE[kl * LSTR + n] = vr[it];
            IM[kl * LSTR + n] = vi[it];
        }
        fft256x16(RE, IM, tid, 1.0f);
        #pragma unroll
        for (int it = 0; it < 16; it++) {
            int n = (tid >> 4) + it * 16;
            if (valid) abase[(size_t)n * plane] =
                make_float2(RE[kl * LSTR + n], IM[kl * LSTR + n]);
        }
    }
}

__global__ void k_irfft_z(const float2* __restrict__ A, float* out, int khp,
                          const float* W, float* __restrict__ S, int fuse) {
    __shared__ __align__(16) float RE[16 * LSTR];
    __shared__ __align__(16) float IM[16 * LSTR];
    __shared__ float red[4];
    int x = blockIdx.x, y0 = blockIdx.y * 16, tid = threadIdx.x;
    #pragma unroll
    for (int l = 0; l < 16; l++) {
        const float2* src = A + (((size_t)x << 8) + (y0 + l)) * khp;
        int n = tid;
        int k = (n <= 128) ? n : 256 - n;
        float2 v = src[k];
        RE[l * LSTR + n] = v.x;
        IM[l * LSTR + n] = (n <= 128) ? v.y : -v.y;
    }
    fft256x16(RE, IM, tid, 1.0f);
    const float sc = 1.0f / 16777216.0f;
    float acc = 0.0f;
    #pragma unroll
    for (int l = 0; l < 16; l++) {
        size_t a = (((size_t)x << 8) + (y0 + l)) * 256 + tid;
        float v = RE[l * LSTR + tid] * sc;
        if (fuse) {
            float wv = W[a];
            acc += v * wv;
        }
        out[a] = v;
    }
    if (fuse) {
        #pragma unroll
        for (int o = 32; o > 0; o >>= 1) acc += __shfl_down(acc, o, 64);
        if ((tid & 63) == 0) red[tid >> 6] = acc;
        __syncthreads();
        if (tid == 0) atomicAdd(S, red[0] + red[1] + red[2] + red[3]);
    }
}

// ---- per-point trilinear interp + sum (gather; == dot(W, phi)).
// Grid-stride + LDS block reduction -> ONE atomic per block (same-address fp32
// atomics serialize at ~30cy; 7816 of them was ~100us — the R8 bottleneck). ----
__global__ void k_interp_sum(const float* __restrict__ phi, const float* __restrict__ V,
                             float* __restrict__ S) {
    __shared__ float red[4];
    float acc = 0.0f;
    for (int i = blockIdx.x * blockDim.x + threadIdx.x; i < NPTS;
         i += gridDim.x * blockDim.x) {
        float xs = V[3 * i + 0] * 256.0f;
        float ys = V[3 * i + 1] * 256.0f;
        float zs = V[3 * i + 2] * 256.0f;
        int ix0 = (int)floorf(xs), iy0 = (int)floorf(ys), iz0 = (int)floorf(zs);
        float fx = xs - (float)ix0, fy = ys - (float)iy0, fz = zs - (float)iz0;
        int ix1 = (ix0 + 1) & 255, iy1 = (iy0 + 1) & 255, iz1 = (iz0 + 1) & 255;
        #pragma unroll
        for (int c = 0; c < 8; c++) {
            int bx = (c >> 2) & 1, by = (c >> 1) & 1, bz = c & 1;
            int ix = bx ? ix1 : ix0, iy = by ? iy1 : iy0, iz = bz ? iz1 : iz0;
            float w = (bx ? fx : 1.0f - fx) * (by ? fy : 1.0f - fy) * (bz ? fz : 1.0f - fz);
            acc += w * phi[(((size_t)ix << 8) + (size_t)iy) * 256 + (size_t)iz];
        }
    }
    #pragma unroll
    for (int o = 32; o > 0; o >>= 1) acc += __shfl_down(acc, o, 64);
    if ((threadIdx.x & 63) == 0) red[threadIdx.x >> 6] = acc;
    __syncthreads();
    if (threadIdx.x == 0) atomicAdd(S, red[0] + red[1] + red[2] + red[3]);
}

__global__ void k_scalars(const float* __restrict__ S, const float* __restrict__ phi,
                          float* __restrict__ sc_out) {
    float mean = S[0] * (1.0f / (float)NPTS);
    sc_out[0] = mean;
    sc_out[1] = 0.5f / fabsf(phi[0] - mean);
}

__global__ void k_scale(float* __restrict__ phi, const float* __restrict__ sc) {
    size_t i = (size_t)blockIdx.x * blockDim.x + threadIdx.x;
    float mean = sc[0], inv = sc[1];
    float4* p = (float4*)phi;
    float4 v = p[i];
    v.x = -(v.x - mean) * inv;
    v.y = -(v.y - mean) * inv;
    v.z = -(v.z - mean) * inv;
    v.w = -(v.w - mean) * inv;
    p[i] = v;
}

extern "C" void kernel_launch(void* const* d_in, const int* in_sizes, int n_in,
                              void* d_out, int out_size, void* d_ws, size_t ws_size,
                              hipStream_t stream) {
    const float* V = (const float*)d_in[0];
    const float* N = (const float*)d_in[1];
    float* out = (float*)d_out;

    const size_t RB   = 256ull * 256 * 256 * 4;               // 64 MiB
    const size_t C129 = 256ull * 256 * 129 * 8;
    const size_t C144 = 256ull * 256 * 144 * 8;
    const size_t SB_CNT = ((NKEY * 4 + 255) / 256) * 256;
    const size_t SB_OFF = (((NKEY + 1) * 4 + 255) / 256) * 256;
    const size_t SB_IDX = ((NPTS * 4 + 255) / 256) * 256;
    const size_t PK_VS  = ((NPTS * 3 * 4 + 255) / 256) * 256;
    const size_t PK_N   = ((NPTS * 4 + 255) / 256) * 256;
    const size_t SORT_CORE = SB_CNT * 2 + SB_OFF;             // cnt + cnt2 + off
    const size_t PACK = PK_VS + 3 * PK_N;

    // mode 2 = truncated tiled path, mode 1 = legacy packed, mode 0 = legacy idx
    int mode, khp; size_t cb;
    if      (ws_size >= RB + 2 * C144 + 256 + SORT_CORE + PACK)   { mode = 2; khp = 144; cb = C144; }
    else if (ws_size >= RB + 2 * C129 + 256 + SORT_CORE + PACK)   { mode = 1; khp = 129; cb = C129; }
    else if (ws_size >= RB + 2 * C144 + 256 + SORT_CORE + SB_IDX) { mode = 0; khp = 144; cb = C144; }
    else if (ws_size >= RB + 2 * C129 + 256 + SORT_CORE + SB_IDX) { mode = 0; khp = 129; cb = C129; }
    else return;

    char* ws = (char*)d_ws;
    float* R0   = (float*)ws;
    float2* C   = (float2*)(ws + RB);
    float2* Acc = (float2*)(ws + RB + cb);
    float*  sc  = (float*)(ws + RB + 2 * cb);                 // [0]=S, [1]=mean, [2]=inv
    char* sb = ws + RB + 2 * cb + 256;
    int* cnt  = (int*)sb;
    int* offp = (int*)(sb + SB_CNT);
    int* cnt2 = (int*)(sb + SB_CNT + SB_OFF);
    char* pb = sb + SORT_CORE;
    float* Vs  = (float*)pb;
    float* Nxp = (float*)(pb + PK_VS);
    float* Nyp = (float*)(pb + PK_VS + PK_N);
    float* Nzp = (float*)(pb + PK_VS + 2 * PK_N);
    int* idx = (int*)pb;   // legacy path reuses pack region

    hipMemsetAsync(sc, 0, 16, stream);
    hipMemsetAsync(cnt, 0, NKEY * 4, stream);

    dim3 b256(256);
    dim3 g_z(256, 16);
    dim3 g_t(256, 9);
    dim3 g_z4(256, 16);
    dim3 g_t4(256, KB4);       // (x | fy-bin, kb)
    dim3 g_x3(128, KB4);       // (yb, kb)
    dim3 g_pts((NPTS + 255) / 256);
    dim3 g_interp(1024);       // grid-stride; 1 atomic per block
    dim3 g_cell(16, 32, 32);   // cz, cy, cx

    k_hist<<<g_pts, b256, 0, stream>>>(V, cnt);
    k_scan<<<1, b256, 0, stream>>>(cnt, offp, cnt2);

    if (mode == 2) {
        k_scatter_pk<<<g_pts, b256, 0, stream>>>(V, N, cnt2, Vs, Nxp, Nyp, Nzp);
        float2* B1 = Acc;              // ch1 compact B (16.8 MB of 75.5)
        float2* B2 = (float2*)out;     // ch2 compact B (front of out; raster consumed first)
        float2* B3 = (float2*)R0;      // ch3 compact B (front of R0; raster consumed first)
        // rasterize walk A (dual): Nx -> R0, Ny -> out
        k_rastg2<<<g_cell, b256, 0, stream>>>(Vs, Nxp, Nyp, offp, R0, out, 0);
        // ch1 (Nx): z -> C:A4, y -> B1
        k_rfft_zA4<<<g_z4, b256, 0, stream>>>(R0, C);
        k_fft_yA_f4<<<g_t4, b256, 0, stream>>>(C, B1);
        // rasterize walk B (single): Nz -> R0 (R0 free after ch1 z-pass)
        k_rastg2<<<g_cell, b256, 0, stream>>>(Vs, Nzp, (const float*)0, offp, R0, (float*)0, 0);
        // ch2 (Ny): z -> C:A4, y -> B2 (overwrites out's raster after z consumed it)
        k_rfft_zA4<<<g_z4, b256, 0, stream>>>(out, C);
        k_fft_yA_f4<<<g_t4, b256, 0, stream>>>(C, B2);
        // ch3 (Nz): z -> C:A4, y -> B3 (overwrites R0's raster after z consumed it)
        k_rfft_zA4<<<g_z4, b256, 0, stream>>>(R0, C);
        k_fft_yA_f4<<<g_t4, b256, 0, stream>>>(C, B3);
        // fused forward-x(3ch) + spectral MAC + inverse-x -> C:A4 kept-fy rows
        k_fft_x3<<<g_x3, b256, 0, stream>>>(B1, B2, B3, C);
        // inverse y (zero-fills dropped fy rows), inverse z
        k_fft_yA_i4<<<g_t4, b256, 0, stream>>>(C);
        k_irfft_zA4<<<g_z4, b256, 0, stream>>>(C, out);
        // mean via gather-interp on sorted coords (== dot(W, phi))
        k_interp_sum<<<g_interp, b256, 0, stream>>>(out, Vs, sc);
    } else if (mode == 1) {
        k_scatter_pk<<<g_pts, b256, 0, stream>>>(V, N, cnt2, Vs, Nxp, Nyp, Nzp);
        k_rastg2<<<g_cell, b256, 0, stream>>>(Vs, Nxp, Nyp, offp, R0, out, 0);
        k_rfft_z<<<g_z, b256, 0, stream>>>(R0, C, khp);
        k_fft_y<<<g_t, b256, 0, stream>>>(C, khp, -1.0f);
        k_fft_x_acc<<<g_t, b256, 0, stream>>>(C, Acc, khp, 0, 0);
        k_rfft_z<<<g_z, b256, 0, stream>>>(out, C, khp);
        k_fft_y<<<g_t, b256, 0, stream>>>(C, khp, -1.0f);
        k_fft_x_acc<<<g_t, b256, 0, stream>>>(C, Acc, khp, 1, 1);
        k_rastg2<<<g_cell, b256, 0, stream>>>(Vs, Nzp, (const float*)0, offp, R0, out, 1);
        k_rfft_z<<<g_z, b256, 0, stream>>>(R0, C, khp);
        k_fft_y<<<g_t, b256, 0, stream>>>(C, khp, -1.0f);
        k_fft_x_acc<<<g_t, b256, 0, stream>>>(C, Acc, khp, 2, 2);
        k_fft_y<<<g_t, b256, 0, stream>>>(Acc, khp, 1.0f);
        k_irfft_z<<<g_z, b256, 0, stream>>>(Acc, out, khp, out, sc, 1);
    } else {
        k_scatter<<<g_pts, b256, 0, stream>>>(V, cnt2, idx);
        for (int d = 0; d < 3; d++) {
            k_rastg<<<g_cell, b256, 0, stream>>>(idx, offp, V, N, R0, d);
            k_rfft_z<<<g_z, b256, 0, stream>>>(R0, C, khp);
            k_fft_y<<<g_t, b256, 0, stream>>>(C, khp, -1.0f);
            k_fft_x_acc<<<g_t, b256, 0, stream>>>(C, Acc, khp, d, d);
        }
        k_fft_y<<<g_t, b256, 0, stream>>>(Acc, khp, 1.0f);
        k_irfft_z<<<g_z, b256, 0, stream>>>(Acc, out, khp, (const float*)0, sc, 0);
        k_interp_sum<<<g_interp, b256, 0, stream>>>(out, V, sc);
    }

    k_scalars<<<1, 1, 0, stream>>>(sc, out, sc + 1);
    k_scale<<<16777216 / 4 / 256, 256, 0, stream>>>(out, sc + 1);
}